// Round 5
// baseline (727.002 us; speedup 1.0000x reference)
//
#include <hip/hip_runtime.h>
#include <hip/hip_bf16.h>
#include <math.h>

#define BB 4
#define SS 2048
#define EE 1024
#define HH 8
#define DD 128
#define BSR (BB*SS)      // 8192 rows
#define HD  (HH*DD)      // 1024
#define LNEPS 1e-5f
#define LOG2E 1.4426950408889634f

typedef __attribute__((ext_vector_type(8))) short bf16x8;
typedef __attribute__((ext_vector_type(4))) float f32x4;

__device__ __forceinline__ ushort f2bf(float f) {
    union { float f; unsigned u; } c{f};
    unsigned r = c.u + 0x7fff + ((c.u >> 16) & 1);   // RNE
    return (ushort)(r >> 16);
}
__device__ __forceinline__ float bf2f(ushort b) {
    union { unsigned u; float f; } c{(unsigned)b << 16};
    return c.f;
}

typedef __attribute__((address_space(1))) const unsigned int GUI;
typedef __attribute__((address_space(3))) unsigned int LUI;
__device__ __forceinline__ void gl_lds16(const ushort* g, ushort* l) {
    __builtin_amdgcn_global_load_lds((GUI*)g, (LUI*)l, 16, 0, 0);
}

// ---------------------------------------------------------------- prep -----
__global__ __launch_bounds__(256)
void prep_k(const float* __restrict__ W2, const float* __restrict__ w_att,
            const float* __restrict__ b2, const float* __restrict__ b_att,
            const float* __restrict__ Uh, const float* __restrict__ Uz,
            const float* __restrict__ Os,
            float* __restrict__ q, float* __restrict__ c,
            float* __restrict__ uh_d, float* __restrict__ uz_d,
            float* __restrict__ os_d)
{
    const int gid  = blockIdx.x * 256 + threadIdx.x;
    const int wave = gid >> 6, lane = gid & 63;
    if (wave < HD) {
        const float* wp = W2 + (size_t)wave * EE;
        float p = 0.f;
        for (int e = lane; e < EE; e += 64) p = fmaf(wp[e], w_att[e], p);
        #pragma unroll
        for (int off = 32; off > 0; off >>= 1) p += __shfl_xor(p, off, 64);
        if (lane == 0) {
            q[wave] = p;
            const int h = wave >> 7, d = wave & 127;
            uh_d[wave] = Uh[(size_t)h*DD*DD + (size_t)d*DD + d];
            uz_d[wave] = Uz[(size_t)h*DD*DD + (size_t)d*DD + d];
            os_d[wave] = Os[(size_t)h*DD*DD + (size_t)d*DD + d];
        }
    } else if (wave < HD + HH) {
        const int h = wave - HD;
        const float* bp = b2 + (size_t)h * EE;
        float p = 0.f;
        for (int e = lane; e < EE; e += 64) p = fmaf(bp[e], w_att[e], p);
        #pragma unroll
        for (int off = 32; off > 0; off >>= 1) p += __shfl_xor(p, off, 64);
        if (lane == 0) c[h] = p + b_att[0];
    }
}

// --------------------------------------- fp32 -> bf16 hi/lo split convert --
__global__ __launch_bounds__(256)
void convx2_k(const float* __restrict__ x,
              ushort* __restrict__ hi, ushort* __restrict__ lo)
{
    const size_t idx = ((size_t)blockIdx.x * 256 + threadIdx.x) * 4;
    const float4 v = *(const float4*)(x + idx);
    ushort4 oh, ol;
    oh.x = f2bf(v.x); ol.x = f2bf(v.x - bf2f(oh.x));
    oh.y = f2bf(v.y); ol.y = f2bf(v.y - bf2f(oh.y));
    oh.z = f2bf(v.z); ol.z = f2bf(v.z - bf2f(oh.z));
    oh.w = f2bf(v.w); ol.w = f2bf(v.w - bf2f(oh.w));
    *(ushort4*)(hi + idx) = oh;
    *(ushort4*)(lo + idx) = ol;
}

// ------------------- transpose + hi/lo split: W[k][n] -> Wt_hi/lo[n][k] ----
__global__ __launch_bounds__(256)
void convT2_k(const float* __restrict__ W,
              ushort* __restrict__ Wth, ushort* __restrict__ Wtl)
{
    __shared__ float tile[32][33];
    const int k0 = blockIdx.x * 32, n0 = blockIdx.y * 32;
    const int tx = threadIdx.x & 31, ty = threadIdx.x >> 5;   // ty 0..7
    #pragma unroll
    for (int i = 0; i < 4; ++i)
        tile[ty + i*8][tx] = W[(size_t)(k0 + ty + i*8) * 1024 + n0 + tx];
    __syncthreads();
    #pragma unroll
    for (int i = 0; i < 4; ++i) {
        const float v = tile[tx][ty + i*8];
        const ushort h = f2bf(v);
        Wth[(size_t)(n0 + ty + i*8) * 1024 + k0 + tx] = h;
        Wtl[(size_t)(n0 + ty + i*8) * 1024 + k0 + tx] = f2bf(v - bf2f(h));
    }
}

// ------------------- transpose + convert (single bf16): W[k][n]->Wt[n][k] --
__global__ __launch_bounds__(256)
void convT_k(const float* __restrict__ W, ushort* __restrict__ Wt)
{
    __shared__ float tile[32][33];
    const int k0 = blockIdx.x * 32, n0 = blockIdx.y * 32;
    const int tx = threadIdx.x & 31, ty = threadIdx.x >> 5;
    #pragma unroll
    for (int i = 0; i < 4; ++i)
        tile[ty + i*8][tx] = W[(size_t)(k0 + ty + i*8) * 1024 + n0 + tx];
    __syncthreads();
    #pragma unroll
    for (int i = 0; i < 4; ++i)
        Wt[(size_t)(n0 + ty + i*8) * 1024 + k0 + tx] = f2bf(tile[tx][ty + i*8]);
}

// -------------- per-head transpose + convert: W1[h][k][n] -> W1t[h][n][k] --
__global__ __launch_bounds__(256)
void convTH_k(const float* __restrict__ W, ushort* __restrict__ Wt)
{
    __shared__ float tile[32][33];
    const int hh = blockIdx.z;
    const int k0 = blockIdx.x * 32, n0 = blockIdx.y * 32;
    const int tx = threadIdx.x & 31, ty = threadIdx.x >> 5;
    const float* Wb = W + (size_t)hh * DD * DD;
    ushort*      Wtb = Wt + (size_t)hh * DD * DD;
    #pragma unroll
    for (int i = 0; i < 4; ++i)
        tile[ty + i*8][tx] = Wb[(size_t)(k0 + ty + i*8) * DD + n0 + tx];
    __syncthreads();
    #pragma unroll
    for (int i = 0; i < 4; ++i)
        Wtb[(size_t)(n0 + ty + i*8) * DD + k0 + tx] = f2bf(tile[tx][ty + i*8]);
}

// ----------------------------------- split-bf16 MFMA GEMM (z, fp32-class) --
__global__ __launch_bounds__(256)
void gemm_mfma_hp(const ushort* __restrict__ Ah, const ushort* __restrict__ Al,
                  const ushort* __restrict__ Bh, const ushort* __restrict__ Bl,
                  float* __restrict__ C, const float* __restrict__ bias)
{
    __shared__ ushort AsmH[128*32], AsmL[128*32];
    __shared__ ushort BsmH[128*32], BsmL[128*32];
    const int t = threadIdx.x, lane = t & 63, w = t >> 6;
    const int wr = w >> 1, wc = w & 1;
    const int row0 = blockIdx.x * 128, col0 = blockIdx.y * 128;

    const int lr = lane >> 2;
    const int lc = (lane & 3) ^ (lr & 3);
    const size_t aoff0 = (size_t)(row0 +      w*16 + lr) * 1024 + lc*8;
    const size_t aoff1 = (size_t)(row0 + 64 + w*16 + lr) * 1024 + lc*8;
    const size_t boff0 = (size_t)(col0 +      w*16 + lr) * 1024 + lc*8;
    const size_t boff1 = (size_t)(col0 + 64 + w*16 + lr) * 1024 + lc*8;
    ushort* AH0 = AsmH + (     w*16) * 32;  ushort* AH1 = AsmH + (64 + w*16) * 32;
    ushort* AL0 = AsmL + (     w*16) * 32;  ushort* AL1 = AsmL + (64 + w*16) * 32;
    ushort* BH0 = BsmH + (     w*16) * 32;  ushort* BH1 = BsmH + (64 + w*16) * 32;
    ushort* BL0 = BsmL + (     w*16) * 32;  ushort* BL1 = BsmL + (64 + w*16) * 32;

    f32x4 acc[4][4];
    #pragma unroll
    for (int i = 0; i < 4; ++i)
        #pragma unroll
        for (int j = 0; j < 4; ++j) acc[i][j] = (f32x4){0.f,0.f,0.f,0.f};

    const int quad = lane >> 4;
    const int fr   = lane & 15;
    const int fchk = (quad ^ (lane & 3)) * 8;

    for (int k0 = 0; k0 < 1024; k0 += 32) {
        __syncthreads();
        gl_lds16(Ah + aoff0 + k0, AH0);
        gl_lds16(Ah + aoff1 + k0, AH1);
        gl_lds16(Bh + boff0 + k0, BH0);
        gl_lds16(Bh + boff1 + k0, BH1);
        gl_lds16(Al + aoff0 + k0, AL0);
        gl_lds16(Al + aoff1 + k0, AL1);
        gl_lds16(Bl + boff0 + k0, BL0);
        gl_lds16(Bl + boff1 + k0, BL1);
        __syncthreads();

        bf16x8 afh[4], afl[4], bfh[4], bfl[4];
        #pragma unroll
        for (int i = 0; i < 4; ++i) {
            const int ra = (wr*64 + i*16 + fr) * 32 + fchk;
            afh[i] = *(const bf16x8*)(AsmH + ra);
            afl[i] = *(const bf16x8*)(AsmL + ra);
            const int rb = (wc*64 + i*16 + fr) * 32 + fchk;
            bfh[i] = *(const bf16x8*)(BsmH + rb);
            bfl[i] = *(const bf16x8*)(BsmL + rb);
        }
        #pragma unroll
        for (int i = 0; i < 4; ++i)
            #pragma unroll
            for (int j = 0; j < 4; ++j) {
                acc[i][j] = __builtin_amdgcn_mfma_f32_16x16x32_bf16(
                    afh[i], bfl[j], acc[i][j], 0, 0, 0);
                acc[i][j] = __builtin_amdgcn_mfma_f32_16x16x32_bf16(
                    afl[i], bfh[j], acc[i][j], 0, 0, 0);
                acc[i][j] = __builtin_amdgcn_mfma_f32_16x16x32_bf16(
                    afh[i], bfh[j], acc[i][j], 0, 0, 0);
            }
    }

    float colv[4];
    #pragma unroll
    for (int tj = 0; tj < 4; ++tj)
        colv[tj] = bias[col0 + wc*64 + tj*16 + fr];
    #pragma unroll
    for (int ti = 0; ti < 4; ++ti)
        #pragma unroll
        for (int i = 0; i < 4; ++i) {
            const int row = row0 + wr*64 + ti*16 + quad*4 + i;
            #pragma unroll
            for (int tj = 0; tj < 4; ++tj) {
                const int col = col0 + wc*64 + tj*16 + fr;
                C[(size_t)row*1024 + col] = tanhf(acc[ti][tj][i] + colv[tj]);
            }
        }
}

// --------------------------------------------------- plain bf16 MFMA GEMM --
// weighted = g @ W2 + sum_h scores[row,h]*b2[h,col]
__global__ __launch_bounds__(256)
void gemm_mfma(const ushort* __restrict__ A, const ushort* __restrict__ Bt,
               float* __restrict__ C,
               const float* __restrict__ scores, const float* __restrict__ b2)
{
    __shared__ ushort Asm[128*32];
    __shared__ ushort Bsm[128*32];
    const int t = threadIdx.x, lane = t & 63, w = t >> 6;
    const int wr = w >> 1, wc = w & 1;
    const int row0 = blockIdx.x * 128, col0 = blockIdx.y * 128;

    const int lr = lane >> 2;
    const int lc = (lane & 3) ^ (lr & 3);
    const ushort* Ag0 = A  + (size_t)(row0 +      w*16 + lr) * 1024 + lc*8;
    const ushort* Ag1 = A  + (size_t)(row0 + 64 + w*16 + lr) * 1024 + lc*8;
    const ushort* Bg0 = Bt + (size_t)(col0 +      w*16 + lr) * 1024 + lc*8;
    const ushort* Bg1 = Bt + (size_t)(col0 + 64 + w*16 + lr) * 1024 + lc*8;
    ushort* Al0 = Asm + (     w*16) * 32;
    ushort* Al1 = Asm + (64 + w*16) * 32;
    ushort* Bl0 = Bsm + (     w*16) * 32;
    ushort* Bl1 = Bsm + (64 + w*16) * 32;

    f32x4 acc[4][4];
    #pragma unroll
    for (int i = 0; i < 4; ++i)
        #pragma unroll
        for (int j = 0; j < 4; ++j) acc[i][j] = (f32x4){0.f,0.f,0.f,0.f};

    const int quad = lane >> 4;
    const int fr   = lane & 15;
    const int fchk = (quad ^ (lane & 3)) * 8;

    for (int k0 = 0; k0 < 1024; k0 += 32) {
        __syncthreads();
        gl_lds16(Ag0 + k0, Al0);
        gl_lds16(Ag1 + k0, Al1);
        gl_lds16(Bg0 + k0, Bl0);
        gl_lds16(Bg1 + k0, Bl1);
        __syncthreads();

        bf16x8 af[4], bf[4];
        #pragma unroll
        for (int i = 0; i < 4; ++i) {
            af[i] = *(const bf16x8*)(Asm + (wr*64 + i*16 + fr)*32 + fchk);
            bf[i] = *(const bf16x8*)(Bsm + (wc*64 + i*16 + fr)*32 + fchk);
        }
        #pragma unroll
        for (int i = 0; i < 4; ++i)
            #pragma unroll
            for (int j = 0; j < 4; ++j)
                acc[i][j] = __builtin_amdgcn_mfma_f32_16x16x32_bf16(
                    af[i], bf[j], acc[i][j], 0, 0, 0);
    }

    float b2v[4][HH];
    #pragma unroll
    for (int tj = 0; tj < 4; ++tj) {
        const int col = col0 + wc*64 + tj*16 + fr;
        #pragma unroll
        for (int h = 0; h < HH; ++h) b2v[tj][h] = b2[(size_t)h*EE + col];
    }
    #pragma unroll
    for (int ti = 0; ti < 4; ++ti)
        #pragma unroll
        for (int i = 0; i < 4; ++i) {
            const int row = row0 + wr*64 + ti*16 + quad*4 + i;
            float sc[HH];
            #pragma unroll
            for (int h = 0; h < HH; ++h) sc[h] = scores[row*HH + h];
            #pragma unroll
            for (int tj = 0; tj < 4; ++tj) {
                const int col = col0 + wc*64 + tj*16 + fr;
                float bb = 0.f;
                #pragma unroll
                for (int h = 0; h < HH; ++h) bb = fmaf(sc[h], b2v[tj][h], bb);
                C[(size_t)row*1024 + col] = acc[ti][tj][i] + bb;
            }
        }
}

// ------------------------- batched per-head MFMA: h1 = gelu(hln@W1[h]+b1) --
// A = hln bf16 [8192][1024] (head slice cols), Bt = W1t[h][n][k] bf16,
// C = h1 fp32 [8192][1024]. M-tile 128, N=128 (full head), K=128, BK=32.
__global__ __launch_bounds__(256)
void gemm_h1(const ushort* __restrict__ A, const ushort* __restrict__ Bt,
             const float* __restrict__ b1, float* __restrict__ C)
{
    const int hh = blockIdx.z;
    __shared__ ushort Asm[128*32];
    __shared__ ushort Bsm[128*32];
    const int t = threadIdx.x, lane = t & 63, w = t >> 6;
    const int wr = w >> 1, wc = w & 1;
    const int row0 = blockIdx.x * 128;

    const int lr = lane >> 2;
    const int lc = (lane & 3) ^ (lr & 3);
    const ushort* Ag0 = A + (size_t)(row0 +      w*16 + lr) * 1024 + hh*DD + lc*8;
    const ushort* Ag1 = A + (size_t)(row0 + 64 + w*16 + lr) * 1024 + hh*DD + lc*8;
    const ushort* Bg0 = Bt + (size_t)hh*DD*DD + (     w*16 + lr) * DD + lc*8;
    const ushort* Bg1 = Bt + (size_t)hh*DD*DD + (64 + w*16 + lr) * DD + lc*8;
    ushort* Al0 = Asm + (     w*16) * 32;
    ushort* Al1 = Asm + (64 + w*16) * 32;
    ushort* Bl0 = Bsm + (     w*16) * 32;
    ushort* Bl1 = Bsm + (64 + w*16) * 32;

    f32x4 acc[4][4];
    #pragma unroll
    for (int i = 0; i < 4; ++i)
        #pragma unroll
        for (int j = 0; j < 4; ++j) acc[i][j] = (f32x4){0.f,0.f,0.f,0.f};

    const int quad = lane >> 4;
    const int fr   = lane & 15;
    const int fchk = (quad ^ (lane & 3)) * 8;

    for (int k0 = 0; k0 < 128; k0 += 32) {
        __syncthreads();
        gl_lds16(Ag0 + k0, Al0);
        gl_lds16(Ag1 + k0, Al1);
        gl_lds16(Bg0 + k0, Bl0);
        gl_lds16(Bg1 + k0, Bl1);
        __syncthreads();

        bf16x8 af[4], bf[4];
        #pragma unroll
        for (int i = 0; i < 4; ++i) {
            af[i] = *(const bf16x8*)(Asm + (wr*64 + i*16 + fr)*32 + fchk);
            bf[i] = *(const bf16x8*)(Bsm + (wc*64 + i*16 + fr)*32 + fchk);
        }
        #pragma unroll
        for (int i = 0; i < 4; ++i)
            #pragma unroll
            for (int j = 0; j < 4; ++j)
                acc[i][j] = __builtin_amdgcn_mfma_f32_16x16x32_bf16(
                    af[i], bf[j], acc[i][j], 0, 0, 0);
    }

    float colv[4];
    #pragma unroll
    for (int tj = 0; tj < 4; ++tj)
        colv[tj] = b1[hh*DD + wc*64 + tj*16 + fr];
    #pragma unroll
    for (int ti = 0; ti < 4; ++ti)
        #pragma unroll
        for (int i = 0; i < 4; ++i) {
            const int row = row0 + wr*64 + ti*16 + quad*4 + i;
            #pragma unroll
            for (int tj = 0; tj < 4; ++tj) {
                const int col = wc*64 + tj*16 + fr;
                float v = acc[ti][tj][i] + colv[tj];
                v = 0.5f * v * (1.f + erff(v * 0.70710678118654752f));
                C[(size_t)row*1024 + hh*DD + col] = v;
            }
        }
}

// ------------------------------------------------- DPP wave reduction ------
__device__ __forceinline__ float dpp_add(float x, const int ctrl) {
    int y;
    switch (ctrl) {
        case 0x111: y = __builtin_amdgcn_update_dpp(0, __float_as_int(x), 0x111, 0xf, 0xf, true); break;
        case 0x112: y = __builtin_amdgcn_update_dpp(0, __float_as_int(x), 0x112, 0xf, 0xf, true); break;
        case 0x114: y = __builtin_amdgcn_update_dpp(0, __float_as_int(x), 0x114, 0xf, 0xf, true); break;
        case 0x118: y = __builtin_amdgcn_update_dpp(0, __float_as_int(x), 0x118, 0xf, 0xf, true); break;
        case 0x142: y = __builtin_amdgcn_update_dpp(0, __float_as_int(x), 0x142, 0xf, 0xf, true); break;
        default:    y = __builtin_amdgcn_update_dpp(0, __float_as_int(x), 0x143, 0xf, 0xf, true); break;
    }
    return x + __int_as_float(y);
}

__device__ __forceinline__ float wave_sum64(float x) {
    x = dpp_add(x, 0x111);
    x = dpp_add(x, 0x112);
    x = dpp_add(x, 0x114);
    x = dpp_add(x, 0x118);
    x = dpp_add(x, 0x142);
    x = dpp_add(x, 0x143);
    return __int_as_float(__builtin_amdgcn_readlane(__float_as_int(x), 63));
}

// ---------------------------------------------------------------- scan -----
// one wave per (b,h); lane owns adjacent pair d=2l,2l+1. Emits hln bf16
// directly: the diag-scale + per-head LN runs OFF the recurrence critical
// path, filling the single-wave SIMD's idle issue slots.
__global__ __launch_bounds__(64)
void scan_k(const float* __restrict__ z,
            const float* __restrict__ uh_d, const float* __restrict__ uz_d,
            const float* __restrict__ b_u,
            const float* __restrict__ lns_g, const float* __restrict__ lns_b,
            const float* __restrict__ os_d,
            const float* __restrict__ ffg, const float* __restrict__ ffb,
            ushort* __restrict__ hln)
{
    const int bh = blockIdx.x;
    const int b = bh >> 3, h = bh & 7;
    const int l = threadIdx.x;
    const int d0 = 2*l, d1 = d0 + 1;

    const float uhn0 = -uh_d[h*DD+d0] * LOG2E, uhn1 = -uh_d[h*DD+d1] * LOG2E;
    const float uzn0 = -uz_d[h*DD+d0] * LOG2E, uzn1 = -uz_d[h*DD+d1] * LOG2E;
    const float bun0 = -b_u [h*DD+d0] * LOG2E, bun1 = -b_u [h*DD+d1] * LOG2E;
    const float g0  = lns_g[d0], g1 = lns_g[d1];
    const float be0 = lns_b[d0], be1 = lns_b[d1];
    const float os0 = os_d[h*DD+d0], os1 = os_d[h*DD+d1];
    const float fg0 = ffg[h*DD+d0],  fg1 = ffg[h*DD+d1];
    const float fb0 = ffb[h*DD+d0],  fb1 = ffb[h*DD+d1];

    const float* zp = z + ((size_t)b * SS * HH + h) * DD + d0;
    unsigned* op = (unsigned*)(hln + (size_t)b * SS * HD + h * DD) + l;

    float hp0 = 0.f, hp1 = 0.f;
    const int CH = 8;
    float2 zc[CH]; float pb0[CH], pb1[CH];
    #pragma unroll
    for (int i = 0; i < CH; ++i) zc[i] = *(const float2*)(zp + (size_t)i*HD);
    #pragma unroll
    for (int i = 0; i < CH; ++i) {
        pb0[i] = fmaf(zc[i].x, uzn0, bun0);
        pb1[i] = fmaf(zc[i].y, uzn1, bun1);
    }

    for (int s0 = 0; s0 < SS; s0 += CH) {
        float2 zn[CH];
        if (s0 + CH < SS) {
            #pragma unroll
            for (int i = 0; i < CH; ++i)
                zn[i] = *(const float2*)(zp + (size_t)(s0+CH+i)*HD);
        } else {
            #pragma unroll
            for (int i = 0; i < CH; ++i) zn[i] = make_float2(0.f, 0.f);
        }
        #pragma unroll
        for (int i = 0; i < CH; ++i) {
            const float z0 = zc[i].x, z1 = zc[i].y;
            const float e0 = __builtin_amdgcn_exp2f(fmaf(hp0, uhn0, pb0[i]));
            const float e1 = __builtin_amdgcn_exp2f(fmaf(hp1, uhn1, pb1[i]));
            const float dv0 = hp0 - z0, dv1 = hp1 - z1;
            const float u0 = __builtin_amdgcn_rcpf(1.f + e0);
            const float u1 = __builtin_amdgcn_rcpf(1.f + e1);
            const float hn0 = fmaf(u0, dv0, z0);
            const float hn1 = fmaf(u1, dv1, z1);
            const float s1 = wave_sum64(hn0 + hn1);
            const float s2 = wave_sum64(fmaf(hn0, hn0, hn1*hn1));
            const float m   = s1 * (1.f/128.f);
            const float var = fmaf(s2, 1.f/128.f, -m*m);
            const float r   = __builtin_amdgcn_rsqf(var + LNEPS);
            const float rg0 = r * g0, rg1 = r * g1;
            hp0 = fmaf(hn0 - m, rg0, be0);
            hp1 = fmaf(hn1 - m, rg1, be1);
            // fused diag-scale + per-head LN (off recurrence path)
            const float y0 = hp0 * os0, y1 = hp1 * os1;
            const float t1 = wave_sum64(y0 + y1);
            const float t2 = wave_sum64(fmaf(y0, y0, y1*y1));
            const float my = t1 * (1.f/128.f);
            const float vy = fmaf(t2, 1.f/128.f, -my*my);
            const float ry = __builtin_amdgcn_rsqf(vy + LNEPS);
            const float o0 = fmaf(y0 - my, ry * fg0, fb0);
            const float o1 = fmaf(y1 - my, ry * fg1, fb1);
            op[(size_t)(s0+i) * (HD/2)] =
                (unsigned)f2bf(o0) | ((unsigned)f2bf(o1) << 16);
        }
        #pragma unroll
        for (int i = 0; i < CH; ++i) {
            zc[i] = zn[i];
            pb0[i] = fmaf(zn[i].x, uzn0, bun0);
            pb1[i] = fmaf(zn[i].y, uzn1, bun1);
        }
    }
}

// ---------------------------------------------------------------- logits ---
__global__ __launch_bounds__(256)
void logits_k(const float* __restrict__ h1, const float* __restrict__ q,
              const float* __restrict__ c, float* __restrict__ logits)
{
    const int gid  = blockIdx.x * 256 + threadIdx.x;
    const int row  = gid >> 6;            // bs*H + h
    const int lane = gid & 63;
    const int h = row & 7;
    const float* xp = h1 + (size_t)row * DD;
    float p = fmaf(xp[lane], q[h*DD + lane], xp[lane+64] * q[h*DD + lane + 64]);
    #pragma unroll
    for (int off = 32; off > 0; off >>= 1) p += __shfl_xor(p, off, 64);
    if (lane == 0) logits[row] = p + c[h];
}

// ------------------------------- softmax + scale h1 -> g (bf16) ------------
__global__ __launch_bounds__(256)
void softscale_k(const float* __restrict__ h1, const float* __restrict__ logits,
                 ushort* __restrict__ gb, float* __restrict__ scores)
{
    const int gid = blockIdx.x * 256 + threadIdx.x;
    const size_t idx = (size_t)gid * 4;
    const int bs = (int)(idx >> 10);
    const int h  = (int)((idx >> 7) & 7);
    float l[8];
    float mx = -1e30f;
    #pragma unroll
    for (int i = 0; i < 8; ++i) { l[i] = logits[bs*8 + i]; mx = fmaxf(mx, l[i]); }
    float den = 0.f;
    #pragma unroll
    for (int i = 0; i < 8; ++i) den += __expf(l[i] - mx);
    const float sc = __expf(l[h] - mx) / den;
    float4 v = *(const float4*)(h1 + idx);
    ushort4 o;
    o.x = f2bf(v.x * sc); o.y = f2bf(v.y * sc);
    o.z = f2bf(v.z * sc); o.w = f2bf(v.w * sc);
    *(ushort4*)(gb + idx) = o;
    if ((idx & 127) == 0) scores[bs*8 + h] = sc;
}

// ---------------------------------------------------------------- final LN -
__global__ __launch_bounds__(256)
void finalln_k(const float* __restrict__ w, const float* __restrict__ g,
               const float* __restrict__ b, float* __restrict__ out)
{
    const int row = blockIdx.x;
    const int t = threadIdx.x;
    const float* xp = w + (size_t)row * EE;
    const float4 v = *(const float4*)(xp + t*4);
    float s1 = v.x + v.y + v.z + v.w;
    float s2 = v.x*v.x + v.y*v.y + v.z*v.z + v.w*v.w;
    #pragma unroll
    for (int off = 32; off > 0; off >>= 1) {
        s1 += __shfl_xor(s1, off, 64);
        s2 += __shfl_xor(s2, off, 64);
    }
    __shared__ float r1[4], r2[4];
    if ((t & 63) == 0) { r1[t>>6] = s1; r2[t>>6] = s2; }
    __syncthreads();
    s1 = r1[0] + r1[1] + r1[2] + r1[3];
    s2 = r2[0] + r2[1] + r2[2] + r2[3];
    const float m   = s1 * (1.f/1024.f);
    const float var = fmaf(s2, 1.f/1024.f, -m*m);
    const float r   = rsqrtf(var + LNEPS);
    const float4 gv = *(const float4*)(g + t*4);
    const float4 bv = *(const float4*)(b + t*4);
    float4 o;
    o.x = fmaf((v.x - m)*r, gv.x, bv.x);
    o.y = fmaf((v.y - m)*r, gv.y, bv.y);
    o.z = fmaf((v.z - m)*r, gv.z, bv.z);
    o.w = fmaf((v.w - m)*r, gv.w, bv.w);
    *(float4*)(out + (size_t)row*EE + t*4) = o;
}

// ---------------------------------------------------------------------------
extern "C" void kernel_launch(void* const* d_in, const int* in_sizes, int n_in,
                              void* d_out, int out_size, void* d_ws, size_t ws_size,
                              hipStream_t stream)
{
    const float* x       = (const float*)d_in[0];
    const float* W_ez    = (const float*)d_in[1];
    const float* b_ez    = (const float*)d_in[2];
    const float* U_h     = (const float*)d_in[3];
    const float* U_z     = (const float*)d_in[4];
    const float* b_u     = (const float*)d_in[5];
    const float* outsh   = (const float*)d_in[6];
    const float* lns_g   = (const float*)d_in[7];
    const float* lns_b   = (const float*)d_in[8];
    const float* ff_ln_g = (const float*)d_in[9];
    const float* ff_ln_b = (const float*)d_in[10];
    const float* ff_W1   = (const float*)d_in[11];
    const float* ff_b1   = (const float*)d_in[12];
    const float* ff_W2   = (const float*)d_in[13];
    const float* ff_b2   = (const float*)d_in[14];
    const float* w_att   = (const float*)d_in[15];
    const float* b_att   = (const float*)d_in[16];
    const float* lno_g   = (const float*)d_in[17];
    const float* lno_b   = (const float*)d_in[18];
    float* out = (float*)d_out;

    float* ws = (float*)d_ws;
    const size_t NBIG = (size_t)BSR * HD;          // 8M floats = 32 MB
    float* bufA = ws;                              // z (fp32) -> gb (bf16)
    float* bufB = ws + NBIG;                       // xb_hi/lo -> hln(bf16) -> weighted(fp32)
    float* bufC = ws + 2*NBIG;                     // WezT hi/lo -> h1 (fp32)
    float* ext  = ws + 3*NBIG;
    ushort* W2t   = (ushort*)ext;                  // 1M ushorts (512K floats)
    ushort* W1t   = (ushort*)(ext + 512*1024);     // 128K ushorts (64K floats)
    float* logits = ext + 512*1024 + 64*1024;      // 64K
    float* scores = logits + BSR*HH;               // 64K
    float* qv     = scores + BSR*HH;               // 1024
    float* cv     = qv + HD;                       // 8
    float* uh_d   = cv + 8;
    float* uz_d   = uh_d + HD;
    float* os_d   = uz_d + HD;
    // lifetime-disjoint aliases:
    ushort* xb_hi = (ushort*)bufB;                 // dies after gemm_mfma_hp
    ushort* xb_lo = (ushort*)bufB + NBIG;
    ushort* hlnb  = (ushort*)bufB;                 // scan out (16 MB), dies after gemm_h1
    float*  wsum  = bufB;                          // weighted (32 MB), after hln dies
    ushort* WezT_hi = (ushort*)bufC;               // die after gemm_mfma_hp
    ushort* WezT_lo = (ushort*)bufC + 1024*1024;
    float*  h1f   = bufC;                          // h1 fp32 after WezT dies
    ushort* gb    = (ushort*)bufA;                 // after z dies

    // 0: independent prep
    convx2_k<<<(BSR*EE/4)/256, 256, 0, stream>>>(x, xb_hi, xb_lo);
    convT2_k<<<dim3(32, 32), 256, 0, stream>>>(W_ez, WezT_hi, WezT_lo);
    convT_k<<<dim3(32, 32), 256, 0, stream>>>(ff_W2, W2t);
    convTH_k<<<dim3(4, 4, 8), 256, 0, stream>>>(ff_W1, W1t);
    prep_k<<<258, 256, 0, stream>>>(ff_W2, w_att, ff_b2, b_att,
                                    U_h, U_z, outsh, qv, cv, uh_d, uz_d, os_d);
    // 1: z = tanh(x @ W_ez + b_ez)   [split-bf16 MFMA, fp32-class]
    gemm_mfma_hp<<<dim3(64, 8), 256, 0, stream>>>(
        xb_hi, xb_lo, WezT_hi, WezT_lo, bufA, b_ez);
    // 2: scan + fused diag-scale + per-head LN -> hln bf16
    scan_k<<<BB*HH, 64, 0, stream>>>(bufA, uh_d, uz_d, b_u, lns_g, lns_b,
                                     os_d, ff_ln_g, ff_ln_b, hlnb);
    // 3: h1 = gelu(hln @ W1[h] + b1[h])  [bf16 MFMA, batched per head]
    gemm_h1<<<dim3(64, 1, 8), 256, 0, stream>>>(hlnb, W1t, ff_b1, h1f);
    // 4: logits = h1 . q[h] + c[h]
    logits_k<<<(BSR*HH*64)/256, 256, 0, stream>>>(h1f, qv, cv, logits);
    // 5: softmax over heads, gb = bf16(score * h1), stash scores
    softscale_k<<<(BSR*HD/4)/256, 256, 0, stream>>>(h1f, logits, gb, scores);
    // 6: weighted = g @ W2 + sum_h score_h*b2[h,:]   [bf16 MFMA]
    gemm_mfma<<<dim3(64, 8), 256, 0, stream>>>(gb, W2t, wsum, scores, ff_b2);
    // 7: final LayerNorm over E -> out
    finalln_k<<<BSR, 256, 0, stream>>>(wsum, lno_g, lno_b, out);
}

// Round 6
// 591.561 us; speedup vs baseline: 1.2290x; 1.2290x over previous
//
#include <hip/hip_runtime.h>
#include <hip/hip_bf16.h>
#include <math.h>

#define BB 4
#define SS 2048
#define EE 1024
#define HH 8
#define DD 128
#define BSR (BB*SS)      // 8192 rows
#define HD  (HH*DD)      // 1024
#define LNEPS 1e-5f
#define LOG2E 1.4426950408889634f

typedef __attribute__((ext_vector_type(8))) short bf16x8;
typedef __attribute__((ext_vector_type(4))) float f32x4;

__device__ __forceinline__ ushort f2bf(float f) {
    union { float f; unsigned u; } c{f};
    unsigned r = c.u + 0x7fff + ((c.u >> 16) & 1);   // RNE
    return (ushort)(r >> 16);
}
__device__ __forceinline__ float bf2f(ushort b) {
    union { unsigned u; float f; } c{(unsigned)b << 16};
    return c.f;
}

typedef __attribute__((address_space(1))) const unsigned int GUI;
typedef __attribute__((address_space(3))) unsigned int LUI;
__device__ __forceinline__ void gl_lds16(const ushort* g, ushort* l) {
    __builtin_amdgcn_global_load_lds((GUI*)g, (LUI*)l, 16, 0, 0);
}

// ---------------------------------------------------------------- prep -----
__global__ __launch_bounds__(256)
void prep_k(const float* __restrict__ W2, const float* __restrict__ w_att,
            const float* __restrict__ b2, const float* __restrict__ b_att,
            const float* __restrict__ Uh, const float* __restrict__ Uz,
            const float* __restrict__ Os,
            float* __restrict__ q, float* __restrict__ c,
            float* __restrict__ uh_d, float* __restrict__ uz_d,
            float* __restrict__ os_d)
{
    const int gid  = blockIdx.x * 256 + threadIdx.x;
    const int wave = gid >> 6, lane = gid & 63;
    if (wave < HD) {
        const float* wp = W2 + (size_t)wave * EE;
        float p = 0.f;
        for (int e = lane; e < EE; e += 64) p = fmaf(wp[e], w_att[e], p);
        #pragma unroll
        for (int off = 32; off > 0; off >>= 1) p += __shfl_xor(p, off, 64);
        if (lane == 0) {
            q[wave] = p;
            const int h = wave >> 7, d = wave & 127;
            uh_d[wave] = Uh[(size_t)h*DD*DD + (size_t)d*DD + d];
            uz_d[wave] = Uz[(size_t)h*DD*DD + (size_t)d*DD + d];
            os_d[wave] = Os[(size_t)h*DD*DD + (size_t)d*DD + d];
        }
    } else if (wave < HD + HH) {
        const int h = wave - HD;
        const float* bp = b2 + (size_t)h * EE;
        float p = 0.f;
        for (int e = lane; e < EE; e += 64) p = fmaf(bp[e], w_att[e], p);
        #pragma unroll
        for (int off = 32; off > 0; off >>= 1) p += __shfl_xor(p, off, 64);
        if (lane == 0) c[h] = p + b_att[0];
    }
}

// --------------------------------------- fp32 -> bf16 hi/lo split convert --
__global__ __launch_bounds__(256)
void convx2_k(const float* __restrict__ x,
              ushort* __restrict__ hi, ushort* __restrict__ lo)
{
    const size_t idx = ((size_t)blockIdx.x * 256 + threadIdx.x) * 4;
    const float4 v = *(const float4*)(x + idx);
    ushort4 oh, ol;
    oh.x = f2bf(v.x); ol.x = f2bf(v.x - bf2f(oh.x));
    oh.y = f2bf(v.y); ol.y = f2bf(v.y - bf2f(oh.y));
    oh.z = f2bf(v.z); ol.z = f2bf(v.z - bf2f(oh.z));
    oh.w = f2bf(v.w); ol.w = f2bf(v.w - bf2f(oh.w));
    *(ushort4*)(hi + idx) = oh;
    *(ushort4*)(lo + idx) = ol;
}

// ------------------- transpose + hi/lo split: W[k][n] -> Wt_hi/lo[n][k] ----
__global__ __launch_bounds__(256)
void convT2_k(const float* __restrict__ W,
              ushort* __restrict__ Wth, ushort* __restrict__ Wtl)
{
    __shared__ float tile[32][33];
    const int k0 = blockIdx.x * 32, n0 = blockIdx.y * 32;
    const int tx = threadIdx.x & 31, ty = threadIdx.x >> 5;   // ty 0..7
    #pragma unroll
    for (int i = 0; i < 4; ++i)
        tile[ty + i*8][tx] = W[(size_t)(k0 + ty + i*8) * 1024 + n0 + tx];
    __syncthreads();
    #pragma unroll
    for (int i = 0; i < 4; ++i) {
        const float v = tile[tx][ty + i*8];
        const ushort h = f2bf(v);
        Wth[(size_t)(n0 + ty + i*8) * 1024 + k0 + tx] = h;
        Wtl[(size_t)(n0 + ty + i*8) * 1024 + k0 + tx] = f2bf(v - bf2f(h));
    }
}

// ------------------- transpose + convert (single bf16): W[k][n]->Wt[n][k] --
__global__ __launch_bounds__(256)
void convT_k(const float* __restrict__ W, ushort* __restrict__ Wt)
{
    __shared__ float tile[32][33];
    const int k0 = blockIdx.x * 32, n0 = blockIdx.y * 32;
    const int tx = threadIdx.x & 31, ty = threadIdx.x >> 5;
    #pragma unroll
    for (int i = 0; i < 4; ++i)
        tile[ty + i*8][tx] = W[(size_t)(k0 + ty + i*8) * 1024 + n0 + tx];
    __syncthreads();
    #pragma unroll
    for (int i = 0; i < 4; ++i)
        Wt[(size_t)(n0 + ty + i*8) * 1024 + k0 + tx] = f2bf(tile[tx][ty + i*8]);
}

// -------------- per-head transpose + convert: W1[h][k][n] -> W1t[h][n][k] --
__global__ __launch_bounds__(256)
void convTH_k(const float* __restrict__ W, ushort* __restrict__ Wt)
{
    __shared__ float tile[32][33];
    const int hh = blockIdx.z;
    const int k0 = blockIdx.x * 32, n0 = blockIdx.y * 32;
    const int tx = threadIdx.x & 31, ty = threadIdx.x >> 5;
    const float* Wb = W + (size_t)hh * DD * DD;
    ushort*      Wtb = Wt + (size_t)hh * DD * DD;
    #pragma unroll
    for (int i = 0; i < 4; ++i)
        tile[ty + i*8][tx] = Wb[(size_t)(k0 + ty + i*8) * DD + n0 + tx];
    __syncthreads();
    #pragma unroll
    for (int i = 0; i < 4; ++i)
        Wtb[(size_t)(n0 + ty + i*8) * DD + k0 + tx] = f2bf(tile[tx][ty + i*8]);
}

// ----------------------------------- split-bf16 MFMA GEMM (z, fp32-class) --
__global__ __launch_bounds__(256)
void gemm_mfma_hp(const ushort* __restrict__ Ah, const ushort* __restrict__ Al,
                  const ushort* __restrict__ Bh, const ushort* __restrict__ Bl,
                  float* __restrict__ C, const float* __restrict__ bias)
{
    __shared__ ushort AsmH[128*32], AsmL[128*32];
    __shared__ ushort BsmH[128*32], BsmL[128*32];
    const int t = threadIdx.x, lane = t & 63, w = t >> 6;
    const int wr = w >> 1, wc = w & 1;
    const int row0 = blockIdx.x * 128, col0 = blockIdx.y * 128;

    const int lr = lane >> 2;
    const int lc = (lane & 3) ^ (lr & 3);
    const size_t aoff0 = (size_t)(row0 +      w*16 + lr) * 1024 + lc*8;
    const size_t aoff1 = (size_t)(row0 + 64 + w*16 + lr) * 1024 + lc*8;
    const size_t boff0 = (size_t)(col0 +      w*16 + lr) * 1024 + lc*8;
    const size_t boff1 = (size_t)(col0 + 64 + w*16 + lr) * 1024 + lc*8;
    ushort* AH0 = AsmH + (     w*16) * 32;  ushort* AH1 = AsmH + (64 + w*16) * 32;
    ushort* AL0 = AsmL + (     w*16) * 32;  ushort* AL1 = AsmL + (64 + w*16) * 32;
    ushort* BH0 = BsmH + (     w*16) * 32;  ushort* BH1 = BsmH + (64 + w*16) * 32;
    ushort* BL0 = BsmL + (     w*16) * 32;  ushort* BL1 = BsmL + (64 + w*16) * 32;

    f32x4 acc[4][4];
    #pragma unroll
    for (int i = 0; i < 4; ++i)
        #pragma unroll
        for (int j = 0; j < 4; ++j) acc[i][j] = (f32x4){0.f,0.f,0.f,0.f};

    const int quad = lane >> 4;
    const int fr   = lane & 15;
    const int fchk = (quad ^ (lane & 3)) * 8;

    for (int k0 = 0; k0 < 1024; k0 += 32) {
        __syncthreads();
        gl_lds16(Ah + aoff0 + k0, AH0);
        gl_lds16(Ah + aoff1 + k0, AH1);
        gl_lds16(Bh + boff0 + k0, BH0);
        gl_lds16(Bh + boff1 + k0, BH1);
        gl_lds16(Al + aoff0 + k0, AL0);
        gl_lds16(Al + aoff1 + k0, AL1);
        gl_lds16(Bl + boff0 + k0, BL0);
        gl_lds16(Bl + boff1 + k0, BL1);
        __syncthreads();

        bf16x8 afh[4], afl[4], bfh[4], bfl[4];
        #pragma unroll
        for (int i = 0; i < 4; ++i) {
            const int ra = (wr*64 + i*16 + fr) * 32 + fchk;
            afh[i] = *(const bf16x8*)(AsmH + ra);
            afl[i] = *(const bf16x8*)(AsmL + ra);
            const int rb = (wc*64 + i*16 + fr) * 32 + fchk;
            bfh[i] = *(const bf16x8*)(BsmH + rb);
            bfl[i] = *(const bf16x8*)(BsmL + rb);
        }
        #pragma unroll
        for (int i = 0; i < 4; ++i)
            #pragma unroll
            for (int j = 0; j < 4; ++j) {
                acc[i][j] = __builtin_amdgcn_mfma_f32_16x16x32_bf16(
                    afh[i], bfl[j], acc[i][j], 0, 0, 0);
                acc[i][j] = __builtin_amdgcn_mfma_f32_16x16x32_bf16(
                    afl[i], bfh[j], acc[i][j], 0, 0, 0);
                acc[i][j] = __builtin_amdgcn_mfma_f32_16x16x32_bf16(
                    afh[i], bfh[j], acc[i][j], 0, 0, 0);
            }
    }

    float colv[4];
    #pragma unroll
    for (int tj = 0; tj < 4; ++tj)
        colv[tj] = bias[col0 + wc*64 + tj*16 + fr];
    #pragma unroll
    for (int ti = 0; ti < 4; ++ti)
        #pragma unroll
        for (int i = 0; i < 4; ++i) {
            const int row = row0 + wr*64 + ti*16 + quad*4 + i;
            #pragma unroll
            for (int tj = 0; tj < 4; ++tj) {
                const int col = col0 + wc*64 + tj*16 + fr;
                C[(size_t)row*1024 + col] = tanhf(acc[ti][tj][i] + colv[tj]);
            }
        }
}

// --------------------------------------------------- plain bf16 MFMA GEMM --
// weighted = g @ W2 + sum_h scores[row,h]*b2[h,col]
__global__ __launch_bounds__(256)
void gemm_mfma(const ushort* __restrict__ A, const ushort* __restrict__ Bt,
               float* __restrict__ C,
               const float* __restrict__ scores, const float* __restrict__ b2)
{
    __shared__ ushort Asm[128*32];
    __shared__ ushort Bsm[128*32];
    const int t = threadIdx.x, lane = t & 63, w = t >> 6;
    const int wr = w >> 1, wc = w & 1;
    const int row0 = blockIdx.x * 128, col0 = blockIdx.y * 128;

    const int lr = lane >> 2;
    const int lc = (lane & 3) ^ (lr & 3);
    const ushort* Ag0 = A  + (size_t)(row0 +      w*16 + lr) * 1024 + lc*8;
    const ushort* Ag1 = A  + (size_t)(row0 + 64 + w*16 + lr) * 1024 + lc*8;
    const ushort* Bg0 = Bt + (size_t)(col0 +      w*16 + lr) * 1024 + lc*8;
    const ushort* Bg1 = Bt + (size_t)(col0 + 64 + w*16 + lr) * 1024 + lc*8;
    ushort* Al0 = Asm + (     w*16) * 32;
    ushort* Al1 = Asm + (64 + w*16) * 32;
    ushort* Bl0 = Bsm + (     w*16) * 32;
    ushort* Bl1 = Bsm + (64 + w*16) * 32;

    f32x4 acc[4][4];
    #pragma unroll
    for (int i = 0; i < 4; ++i)
        #pragma unroll
        for (int j = 0; j < 4; ++j) acc[i][j] = (f32x4){0.f,0.f,0.f,0.f};

    const int quad = lane >> 4;
    const int fr   = lane & 15;
    const int fchk = (quad ^ (lane & 3)) * 8;

    for (int k0 = 0; k0 < 1024; k0 += 32) {
        __syncthreads();
        gl_lds16(Ag0 + k0, Al0);
        gl_lds16(Ag1 + k0, Al1);
        gl_lds16(Bg0 + k0, Bl0);
        gl_lds16(Bg1 + k0, Bl1);
        __syncthreads();

        bf16x8 af[4], bf[4];
        #pragma unroll
        for (int i = 0; i < 4; ++i) {
            af[i] = *(const bf16x8*)(Asm + (wr*64 + i*16 + fr)*32 + fchk);
            bf[i] = *(const bf16x8*)(Bsm + (wc*64 + i*16 + fr)*32 + fchk);
        }
        #pragma unroll
        for (int i = 0; i < 4; ++i)
            #pragma unroll
            for (int j = 0; j < 4; ++j)
                acc[i][j] = __builtin_amdgcn_mfma_f32_16x16x32_bf16(
                    af[i], bf[j], acc[i][j], 0, 0, 0);
    }

    float b2v[4][HH];
    #pragma unroll
    for (int tj = 0; tj < 4; ++tj) {
        const int col = col0 + wc*64 + tj*16 + fr;
        #pragma unroll
        for (int h = 0; h < HH; ++h) b2v[tj][h] = b2[(size_t)h*EE + col];
    }
    #pragma unroll
    for (int ti = 0; ti < 4; ++ti)
        #pragma unroll
        for (int i = 0; i < 4; ++i) {
            const int row = row0 + wr*64 + ti*16 + quad*4 + i;
            float sc[HH];
            #pragma unroll
            for (int h = 0; h < HH; ++h) sc[h] = scores[row*HH + h];
            #pragma unroll
            for (int tj = 0; tj < 4; ++tj) {
                const int col = col0 + wc*64 + tj*16 + fr;
                float bb = 0.f;
                #pragma unroll
                for (int h = 0; h < HH; ++h) bb = fmaf(sc[h], b2v[tj][h], bb);
                C[(size_t)row*1024 + col] = acc[ti][tj][i] + bb;
            }
        }
}

// ------------------------- batched per-head MFMA: h1 = gelu(hln@W1[h]+b1) --
__global__ __launch_bounds__(256)
void gemm_h1(const ushort* __restrict__ A, const ushort* __restrict__ Bt,
             const float* __restrict__ b1, float* __restrict__ C)
{
    const int hh = blockIdx.z;
    __shared__ ushort Asm[128*32];
    __shared__ ushort Bsm[128*32];
    const int t = threadIdx.x, lane = t & 63, w = t >> 6;
    const int wr = w >> 1, wc = w & 1;
    const int row0 = blockIdx.x * 128;

    const int lr = lane >> 2;
    const int lc = (lane & 3) ^ (lr & 3);
    const ushort* Ag0 = A + (size_t)(row0 +      w*16 + lr) * 1024 + hh*DD + lc*8;
    const ushort* Ag1 = A + (size_t)(row0 + 64 + w*16 + lr) * 1024 + hh*DD + lc*8;
    const ushort* Bg0 = Bt + (size_t)hh*DD*DD + (     w*16 + lr) * DD + lc*8;
    const ushort* Bg1 = Bt + (size_t)hh*DD*DD + (64 + w*16 + lr) * DD + lc*8;
    ushort* Al0 = Asm + (     w*16) * 32;
    ushort* Al1 = Asm + (64 + w*16) * 32;
    ushort* Bl0 = Bsm + (     w*16) * 32;
    ushort* Bl1 = Bsm + (64 + w*16) * 32;

    f32x4 acc[4][4];
    #pragma unroll
    for (int i = 0; i < 4; ++i)
        #pragma unroll
        for (int j = 0; j < 4; ++j) acc[i][j] = (f32x4){0.f,0.f,0.f,0.f};

    const int quad = lane >> 4;
    const int fr   = lane & 15;
    const int fchk = (quad ^ (lane & 3)) * 8;

    for (int k0 = 0; k0 < 128; k0 += 32) {
        __syncthreads();
        gl_lds16(Ag0 + k0, Al0);
        gl_lds16(Ag1 + k0, Al1);
        gl_lds16(Bg0 + k0, Bl0);
        gl_lds16(Bg1 + k0, Bl1);
        __syncthreads();

        bf16x8 af[4], bf[4];
        #pragma unroll
        for (int i = 0; i < 4; ++i) {
            af[i] = *(const bf16x8*)(Asm + (wr*64 + i*16 + fr)*32 + fchk);
            bf[i] = *(const bf16x8*)(Bsm + (wc*64 + i*16 + fr)*32 + fchk);
        }
        #pragma unroll
        for (int i = 0; i < 4; ++i)
            #pragma unroll
            for (int j = 0; j < 4; ++j)
                acc[i][j] = __builtin_amdgcn_mfma_f32_16x16x32_bf16(
                    af[i], bf[j], acc[i][j], 0, 0, 0);
    }

    float colv[4];
    #pragma unroll
    for (int tj = 0; tj < 4; ++tj)
        colv[tj] = b1[hh*DD + wc*64 + tj*16 + fr];
    #pragma unroll
    for (int ti = 0; ti < 4; ++ti)
        #pragma unroll
        for (int i = 0; i < 4; ++i) {
            const int row = row0 + wr*64 + ti*16 + quad*4 + i;
            #pragma unroll
            for (int tj = 0; tj < 4; ++tj) {
                const int col = wc*64 + tj*16 + fr;
                float v = acc[ti][tj][i] + colv[tj];
                v = 0.5f * v * (1.f + erff(v * 0.70710678118654752f));
                C[(size_t)row*1024 + hh*DD + col] = v;
            }
        }
}

// ------------------------------------------------- DPP wave reduction ------
__device__ __forceinline__ float dpp_add(float x, const int ctrl) {
    int y;
    switch (ctrl) {
        case 0x111: y = __builtin_amdgcn_update_dpp(0, __float_as_int(x), 0x111, 0xf, 0xf, true); break;
        case 0x112: y = __builtin_amdgcn_update_dpp(0, __float_as_int(x), 0x112, 0xf, 0xf, true); break;
        case 0x114: y = __builtin_amdgcn_update_dpp(0, __float_as_int(x), 0x114, 0xf, 0xf, true); break;
        case 0x118: y = __builtin_amdgcn_update_dpp(0, __float_as_int(x), 0x118, 0xf, 0xf, true); break;
        case 0x142: y = __builtin_amdgcn_update_dpp(0, __float_as_int(x), 0x142, 0xf, 0xf, true); break;
        default:    y = __builtin_amdgcn_update_dpp(0, __float_as_int(x), 0x143, 0xf, 0xf, true); break;
    }
    return x + __int_as_float(y);
}

__device__ __forceinline__ float wave_sum64(float x) {
    x = dpp_add(x, 0x111);
    x = dpp_add(x, 0x112);
    x = dpp_add(x, 0x114);
    x = dpp_add(x, 0x118);
    x = dpp_add(x, 0x142);
    x = dpp_add(x, 0x143);
    return __int_as_float(__builtin_amdgcn_readlane(__float_as_int(x), 63));
}

// ---------------------------------------------------------------- scan -----
// One wave per (b,h); lane owns d=2l,2l+1. States emitted as packed bf16.
// Chain-shortened recurrence: substituting hp=(hn-m)·r·g+be into the next
// gate gives t_next = fma(r, (hn-m)·A, pb) with A=g·uhn const and
// pb = z·uzn + bun + be·uhn — so the critical path is
// rsq -> fma -> exp2 -> rcp -> fma(hn) -> reduce -> rsq; hp/dv/W run in the
// shadow of rsq/exp2. Step 0 peeled (hp=0 breaks the substitution).
__global__ __launch_bounds__(64)
void scan_k(const float* __restrict__ z,
            const float* __restrict__ uh_d, const float* __restrict__ uz_d,
            const float* __restrict__ b_u,
            const float* __restrict__ lns_g, const float* __restrict__ lns_b,
            ushort* __restrict__ states)
{
    const int bh = blockIdx.x;
    const int b = bh >> 3, h = bh & 7;
    const int l = threadIdx.x;
    const int d0 = 2*l, d1 = d0 + 1;

    const float uhn0 = -uh_d[h*DD+d0] * LOG2E, uhn1 = -uh_d[h*DD+d1] * LOG2E;
    const float uzn0 = -uz_d[h*DD+d0] * LOG2E, uzn1 = -uz_d[h*DD+d1] * LOG2E;
    const float bun0 = -b_u [h*DD+d0] * LOG2E, bun1 = -b_u [h*DD+d1] * LOG2E;
    const float g0  = lns_g[d0], g1 = lns_g[d1];
    const float be0 = lns_b[d0], be1 = lns_b[d1];
    const float A0 = g0 * uhn0, A1 = g1 * uhn1;
    const float bunB0 = fmaf(be0, uhn0, bun0);    // bun + be*uhn
    const float bunB1 = fmaf(be1, uhn1, bun1);

    const float* zp = z + ((size_t)b * SS * HH + h) * DD + d0;
    unsigned* op = (unsigned*)(states + (size_t)b * SS * HD + h * DD) + l;

    const int CH = 8;
    float2 zc[CH], zn[CH];
    float pb0[CH], pb1[CH];
    #pragma unroll
    for (int i = 0; i < CH; ++i) zc[i] = *(const float2*)(zp + (size_t)i*HD);
    #pragma unroll
    for (int i = 0; i < CH; ++i) {
        pb0[i] = fmaf(zc[i].x, uzn0, bunB0);
        pb1[i] = fmaf(zc[i].y, uzn1, bunB1);
    }

    float r_c, wp0, wp1, W0, W1, dv0, dv1;

#define SCAN_STEP(ZX, ZY, PB0v, PB1v, ZNX, ZNY, OFF) do {                    \
        const float t0 = fmaf(r_c, W0, (PB0v));                              \
        const float t1 = fmaf(r_c, W1, (PB1v));                              \
        const float e0 = __builtin_amdgcn_exp2f(t0);                         \
        const float e1 = __builtin_amdgcn_exp2f(t1);                         \
        const float u0 = __builtin_amdgcn_rcpf(1.f + e0);                    \
        const float u1 = __builtin_amdgcn_rcpf(1.f + e1);                    \
        const float hn0 = fmaf(u0, dv0, (ZX));                               \
        const float hn1 = fmaf(u1, dv1, (ZY));                               \
        const float s1 = wave_sum64(hn0 + hn1);                              \
        const float s2 = wave_sum64(fmaf(hn0, hn0, hn1*hn1));                \
        const float m   = s1 * (1.f/128.f);                                  \
        const float var = fmaf(s2, 1.f/128.f, -m*m);                         \
        r_c = __builtin_amdgcn_rsqf(var + LNEPS);                            \
        wp0 = hn0 - m; wp1 = hn1 - m;                                        \
        W0 = wp0 * A0; W1 = wp1 * A1;                                        \
        const float hp0 = fmaf(wp0, r_c * g0, be0);                          \
        const float hp1 = fmaf(wp1, r_c * g1, be1);                          \
        op[(size_t)(OFF) * (HD/2)] =                                         \
            (unsigned)f2bf(hp0) | ((unsigned)f2bf(hp1) << 16);               \
        dv0 = hp0 - (ZNX); dv1 = hp1 - (ZNY);                                \
    } while (0)

    // ---- peel step 0 (h_prev = 0) ----
    {
        const float z0 = zc[0].x, z1 = zc[0].y;
        const float t0 = fmaf(z0, uzn0, bun0);     // raw pre, no be*uhn term
        const float t1 = fmaf(z1, uzn1, bun1);
        const float e0 = __builtin_amdgcn_exp2f(t0);
        const float e1 = __builtin_amdgcn_exp2f(t1);
        const float u0 = __builtin_amdgcn_rcpf(1.f + e0);
        const float u1 = __builtin_amdgcn_rcpf(1.f + e1);
        const float hn0 = fmaf(u0, -z0, z0);       // u*(0-z)+z
        const float hn1 = fmaf(u1, -z1, z1);
        const float s1 = wave_sum64(hn0 + hn1);
        const float s2 = wave_sum64(fmaf(hn0, hn0, hn1*hn1));
        const float m   = s1 * (1.f/128.f);
        const float var = fmaf(s2, 1.f/128.f, -m*m);
        r_c = __builtin_amdgcn_rsqf(var + LNEPS);
        wp0 = hn0 - m; wp1 = hn1 - m;
        W0 = wp0 * A0; W1 = wp1 * A1;
        const float hp0 = fmaf(wp0, r_c * g0, be0);
        const float hp1 = fmaf(wp1, r_c * g1, be1);
        op[0] = (unsigned)f2bf(hp0) | ((unsigned)f2bf(hp1) << 16);
        dv0 = hp0 - zc[1].x; dv1 = hp1 - zc[1].y;
    }

    // ---- rest of chunk 0 (steps 1..7) ----
    #pragma unroll
    for (int i = 0; i < CH; ++i)
        zn[i] = *(const float2*)(zp + (size_t)(CH+i)*HD);
    #pragma unroll
    for (int i = 1; i < CH; ++i) {
        const float znx = (i+1 < CH) ? zc[i+1].x : zn[0].x;
        const float zny = (i+1 < CH) ? zc[i+1].y : zn[0].y;
        SCAN_STEP(zc[i].x, zc[i].y, pb0[i], pb1[i], znx, zny, i);
    }
    #pragma unroll
    for (int i = 0; i < CH; ++i) {
        zc[i] = zn[i];
        pb0[i] = fmaf(zn[i].x, uzn0, bunB0);
        pb1[i] = fmaf(zn[i].y, uzn1, bunB1);
    }

    // ---- chunks 1..255 ----
    for (int s0 = CH; s0 < SS; s0 += CH) {
        if (s0 + CH < SS) {
            #pragma unroll
            for (int i = 0; i < CH; ++i)
                zn[i] = *(const float2*)(zp + (size_t)(s0+CH+i)*HD);
        } else {
            #pragma unroll
            for (int i = 0; i < CH; ++i) zn[i] = make_float2(0.f, 0.f);
        }
        #pragma unroll
        for (int i = 0; i < CH; ++i) {
            const float znx = (i+1 < CH) ? zc[i+1].x : zn[0].x;
            const float zny = (i+1 < CH) ? zc[i+1].y : zn[0].y;
            SCAN_STEP(zc[i].x, zc[i].y, pb0[i], pb1[i], znx, zny, s0 + i);
        }
        #pragma unroll
        for (int i = 0; i < CH; ++i) {
            zc[i] = zn[i];
            pb0[i] = fmaf(zn[i].x, uzn0, bunB0);
            pb1[i] = fmaf(zn[i].y, uzn1, bunB1);
        }
    }
#undef SCAN_STEP
}

// ------------------- per-head diag+LN: bf16 states -> bf16 hln -------------
__global__ __launch_bounds__(256)
void headln_k(const unsigned* __restrict__ st, const float* __restrict__ os_d,
              const float* __restrict__ ffg, const float* __restrict__ ffb,
              unsigned* __restrict__ hln)
{
    const int gid  = blockIdx.x * 256 + threadIdx.x;
    const int row  = gid >> 6;            // bs*H + h  (< 65536)
    const int l    = gid & 63;
    const int h = row & 7;
    const int d0 = 2*l, d1 = d0 + 1;
    const unsigned v = st[(size_t)row * 64 + l];
    const float x0 = bf2f((ushort)(v & 0xffff)) * os_d[h*DD + d0];
    const float x1 = bf2f((ushort)(v >> 16))    * os_d[h*DD + d1];
    float s1 = x0 + x1;
    float s2 = fmaf(x0, x0, x1*x1);
    #pragma unroll
    for (int off = 32; off > 0; off >>= 1) {
        s1 += __shfl_xor(s1, off, 64);
        s2 += __shfl_xor(s2, off, 64);
    }
    const float m   = s1 * (1.f/128.f);
    const float var = fmaf(s2, 1.f/128.f, -m*m);
    const float r   = rsqrtf(var + LNEPS);
    const float o0 = fmaf((x0 - m)*r, ffg[h*DD + d0], ffb[h*DD + d0]);
    const float o1 = fmaf((x1 - m)*r, ffg[h*DD + d1], ffb[h*DD + d1]);
    hln[(size_t)row * 64 + l] = (unsigned)f2bf(o0) | ((unsigned)f2bf(o1) << 16);
}

// ---------------------------------------------------------------- logits ---
__global__ __launch_bounds__(256)
void logits_k(const float* __restrict__ h1, const float* __restrict__ q,
              const float* __restrict__ c, float* __restrict__ logits)
{
    const int gid  = blockIdx.x * 256 + threadIdx.x;
    const int row  = gid >> 6;            // bs*H + h
    const int lane = gid & 63;
    const int h = row & 7;
    const float* xp = h1 + (size_t)row * DD;
    float p = fmaf(xp[lane], q[h*DD + lane], xp[lane+64] * q[h*DD + lane + 64]);
    #pragma unroll
    for (int off = 32; off > 0; off >>= 1) p += __shfl_xor(p, off, 64);
    if (lane == 0) logits[row] = p + c[h];
}

// ------------------------------- softmax + scale h1 -> g (bf16) ------------
__global__ __launch_bounds__(256)
void softscale_k(const float* __restrict__ h1, const float* __restrict__ logits,
                 ushort* __restrict__ gb, float* __restrict__ scores)
{
    const int gid = blockIdx.x * 256 + threadIdx.x;
    const size_t idx = (size_t)gid * 4;
    const int bs = (int)(idx >> 10);
    const int h  = (int)((idx >> 7) & 7);
    float l[8];
    float mx = -1e30f;
    #pragma unroll
    for (int i = 0; i < 8; ++i) { l[i] = logits[bs*8 + i]; mx = fmaxf(mx, l[i]); }
    float den = 0.f;
    #pragma unroll
    for (int i = 0; i < 8; ++i) den += __expf(l[i] - mx);
    const float sc = __expf(l[h] - mx) / den;
    float4 v = *(const float4*)(h1 + idx);
    ushort4 o;
    o.x = f2bf(v.x * sc); o.y = f2bf(v.y * sc);
    o.z = f2bf(v.z * sc); o.w = f2bf(v.w * sc);
    *(ushort4*)(gb + idx) = o;
    if ((idx & 127) == 0) scores[bs*8 + h] = sc;
}

// ---------------------------------------------------------------- final LN -
__global__ __launch_bounds__(256)
void finalln_k(const float* __restrict__ w, const float* __restrict__ g,
               const float* __restrict__ b, float* __restrict__ out)
{
    const int row = blockIdx.x;
    const int t = threadIdx.x;
    const float* xp = w + (size_t)row * EE;
    const float4 v = *(const float4*)(xp + t*4);
    float s1 = v.x + v.y + v.z + v.w;
    float s2 = v.x*v.x + v.y*v.y + v.z*v.z + v.w*v.w;
    #pragma unroll
    for (int off = 32; off > 0; off >>= 1) {
        s1 += __shfl_xor(s1, off, 64);
        s2 += __shfl_xor(s2, off, 64);
    }
    __shared__ float r1[4], r2[4];
    if ((t & 63) == 0) { r1[t>>6] = s1; r2[t>>6] = s2; }
    __syncthreads();
    s1 = r1[0] + r1[1] + r1[2] + r1[3];
    s2 = r2[0] + r2[1] + r2[2] + r2[3];
    const float m   = s1 * (1.f/1024.f);
    const float var = fmaf(s2, 1.f/1024.f, -m*m);
    const float r   = rsqrtf(var + LNEPS);
    const float4 gv = *(const float4*)(g + t*4);
    const float4 bv = *(const float4*)(b + t*4);
    float4 o;
    o.x = fmaf((v.x - m)*r, gv.x, bv.x);
    o.y = fmaf((v.y - m)*r, gv.y, bv.y);
    o.z = fmaf((v.z - m)*r, gv.z, bv.z);
    o.w = fmaf((v.w - m)*r, gv.w, bv.w);
    *(float4*)(out + (size_t)row*EE + t*4) = o;
}

// ---------------------------------------------------------------------------
extern "C" void kernel_launch(void* const* d_in, const int* in_sizes, int n_in,
                              void* d_out, int out_size, void* d_ws, size_t ws_size,
                              hipStream_t stream)
{
    const float* x       = (const float*)d_in[0];
    const float* W_ez    = (const float*)d_in[1];
    const float* b_ez    = (const float*)d_in[2];
    const float* U_h     = (const float*)d_in[3];
    const float* U_z     = (const float*)d_in[4];
    const float* b_u     = (const float*)d_in[5];
    const float* outsh   = (const float*)d_in[6];
    const float* lns_g   = (const float*)d_in[7];
    const float* lns_b   = (const float*)d_in[8];
    const float* ff_ln_g = (const float*)d_in[9];
    const float* ff_ln_b = (const float*)d_in[10];
    const float* ff_W1   = (const float*)d_in[11];
    const float* ff_b1   = (const float*)d_in[12];
    const float* ff_W2   = (const float*)d_in[13];
    const float* ff_b2   = (const float*)d_in[14];
    const float* w_att   = (const float*)d_in[15];
    const float* b_att   = (const float*)d_in[16];
    const float* lno_g   = (const float*)d_in[17];
    const float* lno_b   = (const float*)d_in[18];
    float* out = (float*)d_out;

    float* ws = (float*)d_ws;
    const size_t NBIG = (size_t)BSR * HD;          // 8M floats = 32 MB
    float* bufA = ws;                              // z (fp32) -> gb (bf16)
    float* bufB = ws + NBIG;                       // xb_hi/lo -> states+hln (bf16) -> weighted
    float* bufC = ws + 2*NBIG;                     // WezT hi/lo -> h1 (fp32)
    float* ext  = ws + 3*NBIG;
    ushort* W2t   = (ushort*)ext;                  // 1M ushorts (512K floats)
    ushort* W1t   = (ushort*)(ext + 512*1024);     // 128K ushorts (64K floats)
    float* logits = ext + 512*1024 + 64*1024;      // 64K
    float* scores = logits + BSR*HH;               // 64K
    float* qv     = scores + BSR*HH;               // 1024
    float* cv     = qv + HD;                       // 8
    float* uh_d   = cv + 8;
    float* uz_d   = uh_d + HD;
    float* os_d   = uz_d + HD;
    // lifetime-disjoint aliases:
    ushort* xb_hi = (ushort*)bufB;                 // dies after gemm_mfma_hp
    ushort* xb_lo = (ushort*)bufB + NBIG;
    ushort* stb   = (ushort*)bufB;                 // scan out (16 MB, packed bf16)
    ushort* hlnb  = (ushort*)bufB + NBIG;          // headln out (16 MB)
    float*  wsum  = bufB;                          // weighted (32 MB), after st/hln die
    ushort* WezT_hi = (ushort*)bufC;               // die after gemm_mfma_hp
    ushort* WezT_lo = (ushort*)bufC + 1024*1024;
    float*  h1f   = bufC;                          // h1 fp32 after WezT dies
    ushort* gb    = (ushort*)bufA;                 // after z dies

    // 0: independent prep
    convx2_k<<<(BSR*EE/4)/256, 256, 0, stream>>>(x, xb_hi, xb_lo);
    convT2_k<<<dim3(32, 32), 256, 0, stream>>>(W_ez, WezT_hi, WezT_lo);
    convT_k<<<dim3(32, 32), 256, 0, stream>>>(ff_W2, W2t);
    convTH_k<<<dim3(4, 4, 8), 256, 0, stream>>>(ff_W1, W1t);
    prep_k<<<258, 256, 0, stream>>>(ff_W2, w_att, ff_b2, b_att,
                                    U_h, U_z, outsh, qv, cv, uh_d, uz_d, os_d);
    // 1: z = tanh(x @ W_ez + b_ez)   [split-bf16 MFMA, fp32-class]
    gemm_mfma_hp<<<dim3(64, 8), 256, 0, stream>>>(
        xb_hi, xb_lo, WezT_hi, WezT_lo, bufA, b_ez);
    // 2: scan -> states (packed bf16)
    scan_k<<<BB*HH, 64, 0, stream>>>(bufA, uh_d, uz_d, b_u, lns_g, lns_b, stb);
    // 3: diag-scale + per-head LN -> hln bf16
    headln_k<<<(BSR*HH*64)/256, 256, 0, stream>>>(
        (const unsigned*)stb, os_d, ff_ln_g, ff_ln_b, (unsigned*)hlnb);
    // 4: h1 = gelu(hln @ W1[h] + b1[h])  [bf16 MFMA, batched per head]
    gemm_h1<<<dim3(64, 1, 8), 256, 0, stream>>>(hlnb, W1t, ff_b1, h1f);
    // 5: logits = h1 . q[h] + c[h]
    logits_k<<<(BSR*HH*64)/256, 256, 0, stream>>>(h1f, qv, cv, logits);
    // 6: softmax over heads, gb = bf16(score * h1), stash scores
    softscale_k<<<(BSR*HD/4)/256, 256, 0, stream>>>(h1f, logits, gb, scores);
    // 7: weighted = g @ W2 + sum_h score_h*b2[h,:]   [bf16 MFMA]
    gemm_mfma<<<dim3(64, 8), 256, 0, stream>>>(gb, W2t, wsum, scores, ff_b2);
    // 8: final LayerNorm over E -> out
    finalln_k<<<BSR, 256, 0, stream>>>(wsum, lno_g, lno_b, out);
}

// Round 7
// 566.893 us; speedup vs baseline: 1.2824x; 1.0435x over previous
//
#include <hip/hip_runtime.h>
#include <hip/hip_bf16.h>
#include <math.h>

#define BB 4
#define SS 2048
#define EE 1024
#define HH 8
#define DD 128
#define BSR (BB*SS)      // 8192 rows
#define HD  (HH*DD)      // 1024
#define LNEPS 1e-5f
#define LOG2E 1.4426950408889634f

typedef __attribute__((ext_vector_type(8))) short bf16x8;
typedef __attribute__((ext_vector_type(4))) float f32x4;

__device__ __forceinline__ ushort f2bf(float f) {
    union { float f; unsigned u; } c{f};
    unsigned r = c.u + 0x7fff + ((c.u >> 16) & 1);   // RNE
    return (ushort)(r >> 16);
}
__device__ __forceinline__ float bf2f(ushort b) {
    union { unsigned u; float f; } c{(unsigned)b << 16};
    return c.f;
}

typedef __attribute__((address_space(1))) const unsigned int GUI;
typedef __attribute__((address_space(3))) unsigned int LUI;
__device__ __forceinline__ void gl_lds16(const ushort* g, ushort* l) {
    __builtin_amdgcn_global_load_lds((GUI*)g, (LUI*)l, 16, 0, 0);
}

// ------------------------------------------------- DPP wave reduction ------
__device__ __forceinline__ float dpp_add(float x, const int ctrl) {
    int y;
    switch (ctrl) {
        case 0x111: y = __builtin_amdgcn_update_dpp(0, __float_as_int(x), 0x111, 0xf, 0xf, true); break;
        case 0x112: y = __builtin_amdgcn_update_dpp(0, __float_as_int(x), 0x112, 0xf, 0xf, true); break;
        case 0x114: y = __builtin_amdgcn_update_dpp(0, __float_as_int(x), 0x114, 0xf, 0xf, true); break;
        case 0x118: y = __builtin_amdgcn_update_dpp(0, __float_as_int(x), 0x118, 0xf, 0xf, true); break;
        case 0x142: y = __builtin_amdgcn_update_dpp(0, __float_as_int(x), 0x142, 0xf, 0xf, true); break;
        default:    y = __builtin_amdgcn_update_dpp(0, __float_as_int(x), 0x143, 0xf, 0xf, true); break;
    }
    return x + __int_as_float(y);
}

__device__ __forceinline__ float wave_sum64(float x) {
    x = dpp_add(x, 0x111);
    x = dpp_add(x, 0x112);
    x = dpp_add(x, 0x114);
    x = dpp_add(x, 0x118);
    x = dpp_add(x, 0x142);
    x = dpp_add(x, 0x143);
    return __int_as_float(__builtin_amdgcn_readlane(__float_as_int(x), 63));
}

// --------------------------------------- fp32 -> bf16 hi/lo split convert --
__global__ __launch_bounds__(256)
void convx2_k(const float* __restrict__ x,
              ushort* __restrict__ hi, ushort* __restrict__ lo)
{
    const size_t idx = ((size_t)blockIdx.x * 256 + threadIdx.x) * 4;
    const float4 v = *(const float4*)(x + idx);
    ushort4 oh, ol;
    oh.x = f2bf(v.x); ol.x = f2bf(v.x - bf2f(oh.x));
    oh.y = f2bf(v.y); ol.y = f2bf(v.y - bf2f(oh.y));
    oh.z = f2bf(v.z); ol.z = f2bf(v.z - bf2f(oh.z));
    oh.w = f2bf(v.w); ol.w = f2bf(v.w - bf2f(oh.w));
    *(ushort4*)(hi + idx) = oh;
    *(ushort4*)(lo + idx) = ol;
}

// ---------------------- merged weight prep (transposes + diagonals + q/c) --
// blocks [0,1024)    : W_ez -> WezT hi/lo (32x32 transpose tiles)
// blocks [1024,2048) : ff_W2 -> W2t bf16
// blocks [2048,2176) : ff_W1[h] -> W1t bf16 (per-head transpose)
// blocks [2176,2434) : q = W2 . w_att, c, uh/uz/os diagonals
__global__ __launch_bounds__(256)
void prepall_k(const float* __restrict__ W_ez,
               ushort* __restrict__ Wth, ushort* __restrict__ Wtl,
               const float* __restrict__ W2, ushort* __restrict__ W2t,
               const float* __restrict__ W1, ushort* __restrict__ W1t,
               const float* __restrict__ w_att, const float* __restrict__ b2,
               const float* __restrict__ b_att,
               const float* __restrict__ Uh, const float* __restrict__ Uz,
               const float* __restrict__ Os,
               float* __restrict__ q, float* __restrict__ c,
               float* __restrict__ uh_d, float* __restrict__ uz_d,
               float* __restrict__ os_d)
{
    __shared__ float tile[32][33];
    const int blk = blockIdx.x;
    const int tx = threadIdx.x & 31, ty = threadIdx.x >> 5;   // ty 0..7
    if (blk < 1024) {
        const int k0 = (blk >> 5) * 32, n0 = (blk & 31) * 32;
        #pragma unroll
        for (int i = 0; i < 4; ++i)
            tile[ty + i*8][tx] = W_ez[(size_t)(k0 + ty + i*8) * 1024 + n0 + tx];
        __syncthreads();
        #pragma unroll
        for (int i = 0; i < 4; ++i) {
            const float v = tile[tx][ty + i*8];
            const ushort h = f2bf(v);
            Wth[(size_t)(n0 + ty + i*8) * 1024 + k0 + tx] = h;
            Wtl[(size_t)(n0 + ty + i*8) * 1024 + k0 + tx] = f2bf(v - bf2f(h));
        }
    } else if (blk < 2048) {
        const int b2i = blk - 1024;
        const int k0 = (b2i >> 5) * 32, n0 = (b2i & 31) * 32;
        #pragma unroll
        for (int i = 0; i < 4; ++i)
            tile[ty + i*8][tx] = W2[(size_t)(k0 + ty + i*8) * 1024 + n0 + tx];
        __syncthreads();
        #pragma unroll
        for (int i = 0; i < 4; ++i)
            W2t[(size_t)(n0 + ty + i*8) * 1024 + k0 + tx] = f2bf(tile[tx][ty + i*8]);
    } else if (blk < 2176) {
        const int idx = blk - 2048;
        const int hh = idx >> 4;
        const int k0 = (idx & 3) * 32, n0 = ((idx >> 2) & 3) * 32;
        const float* Wb = W1 + (size_t)hh * DD * DD;
        ushort*      Wtb = W1t + (size_t)hh * DD * DD;
        #pragma unroll
        for (int i = 0; i < 4; ++i)
            tile[ty + i*8][tx] = Wb[(size_t)(k0 + ty + i*8) * DD + n0 + tx];
        __syncthreads();
        #pragma unroll
        for (int i = 0; i < 4; ++i)
            Wtb[(size_t)(n0 + ty + i*8) * DD + k0 + tx] = f2bf(tile[tx][ty + i*8]);
    } else {
        const int gid  = (blk - 2176) * 256 + threadIdx.x;
        const int wave = gid >> 6, lane = gid & 63;
        if (wave < HD) {
            const float* wp = W2 + (size_t)wave * EE;
            float p = 0.f;
            for (int e = lane; e < EE; e += 64) p = fmaf(wp[e], w_att[e], p);
            #pragma unroll
            for (int off = 32; off > 0; off >>= 1) p += __shfl_xor(p, off, 64);
            if (lane == 0) {
                q[wave] = p;
                const int h = wave >> 7, d = wave & 127;
                uh_d[wave] = Uh[(size_t)h*DD*DD + (size_t)d*DD + d];
                uz_d[wave] = Uz[(size_t)h*DD*DD + (size_t)d*DD + d];
                os_d[wave] = Os[(size_t)h*DD*DD + (size_t)d*DD + d];
            }
        } else if (wave < HD + HH) {
            const int h = wave - HD;
            const float* bp = b2 + (size_t)h * EE;
            float p = 0.f;
            for (int e = lane; e < EE; e += 64) p = fmaf(bp[e], w_att[e], p);
            #pragma unroll
            for (int off = 32; off > 0; off >>= 1) p += __shfl_xor(p, off, 64);
            if (lane == 0) c[h] = p + b_att[0];
        }
    }
}

// ----------------------------------- split-bf16 MFMA GEMM (z, fp32-class) --
__global__ __launch_bounds__(256)
void gemm_mfma_hp(const ushort* __restrict__ Ah, const ushort* __restrict__ Al,
                  const ushort* __restrict__ Bh, const ushort* __restrict__ Bl,
                  float* __restrict__ C, const float* __restrict__ bias)
{
    __shared__ ushort AsmH[128*32], AsmL[128*32];
    __shared__ ushort BsmH[128*32], BsmL[128*32];
    const int t = threadIdx.x, lane = t & 63, w = t >> 6;
    const int wr = w >> 1, wc = w & 1;
    const int row0 = blockIdx.x * 128, col0 = blockIdx.y * 128;

    const int lr = lane >> 2;
    const int lc = (lane & 3) ^ (lr & 3);
    const size_t aoff0 = (size_t)(row0 +      w*16 + lr) * 1024 + lc*8;
    const size_t aoff1 = (size_t)(row0 + 64 + w*16 + lr) * 1024 + lc*8;
    const size_t boff0 = (size_t)(col0 +      w*16 + lr) * 1024 + lc*8;
    const size_t boff1 = (size_t)(col0 + 64 + w*16 + lr) * 1024 + lc*8;
    ushort* AH0 = AsmH + (     w*16) * 32;  ushort* AH1 = AsmH + (64 + w*16) * 32;
    ushort* AL0 = AsmL + (     w*16) * 32;  ushort* AL1 = AsmL + (64 + w*16) * 32;
    ushort* BH0 = BsmH + (     w*16) * 32;  ushort* BH1 = BsmH + (64 + w*16) * 32;
    ushort* BL0 = BsmL + (     w*16) * 32;  ushort* BL1 = BsmL + (64 + w*16) * 32;

    f32x4 acc[4][4];
    #pragma unroll
    for (int i = 0; i < 4; ++i)
        #pragma unroll
        for (int j = 0; j < 4; ++j) acc[i][j] = (f32x4){0.f,0.f,0.f,0.f};

    const int quad = lane >> 4;
    const int fr   = lane & 15;
    const int fchk = (quad ^ (lane & 3)) * 8;

    for (int k0 = 0; k0 < 1024; k0 += 32) {
        __syncthreads();
        gl_lds16(Ah + aoff0 + k0, AH0);
        gl_lds16(Ah + aoff1 + k0, AH1);
        gl_lds16(Bh + boff0 + k0, BH0);
        gl_lds16(Bh + boff1 + k0, BH1);
        gl_lds16(Al + aoff0 + k0, AL0);
        gl_lds16(Al + aoff1 + k0, AL1);
        gl_lds16(Bl + boff0 + k0, BL0);
        gl_lds16(Bl + boff1 + k0, BL1);
        __syncthreads();

        bf16x8 afh[4], afl[4], bfh[4], bfl[4];
        #pragma unroll
        for (int i = 0; i < 4; ++i) {
            const int ra = (wr*64 + i*16 + fr) * 32 + fchk;
            afh[i] = *(const bf16x8*)(AsmH + ra);
            afl[i] = *(const bf16x8*)(AsmL + ra);
            const int rb = (wc*64 + i*16 + fr) * 32 + fchk;
            bfh[i] = *(const bf16x8*)(BsmH + rb);
            bfl[i] = *(const bf16x8*)(BsmL + rb);
        }
        #pragma unroll
        for (int i = 0; i < 4; ++i)
            #pragma unroll
            for (int j = 0; j < 4; ++j) {
                acc[i][j] = __builtin_amdgcn_mfma_f32_16x16x32_bf16(
                    afh[i], bfl[j], acc[i][j], 0, 0, 0);
                acc[i][j] = __builtin_amdgcn_mfma_f32_16x16x32_bf16(
                    afl[i], bfh[j], acc[i][j], 0, 0, 0);
                acc[i][j] = __builtin_amdgcn_mfma_f32_16x16x32_bf16(
                    afh[i], bfh[j], acc[i][j], 0, 0, 0);
            }
    }

    float colv[4];
    #pragma unroll
    for (int tj = 0; tj < 4; ++tj)
        colv[tj] = bias[col0 + wc*64 + tj*16 + fr];
    #pragma unroll
    for (int ti = 0; ti < 4; ++ti)
        #pragma unroll
        for (int i = 0; i < 4; ++i) {
            const int row = row0 + wr*64 + ti*16 + quad*4 + i;
            #pragma unroll
            for (int tj = 0; tj < 4; ++tj) {
                const int col = col0 + wc*64 + tj*16 + fr;
                C[(size_t)row*1024 + col] = tanhf(acc[ti][tj][i] + colv[tj]);
            }
        }
}

// --------------------------------------------------- plain bf16 MFMA GEMM --
// weighted = g @ W2 + sum_h scores[row,h]*b2[h,col]
__global__ __launch_bounds__(256)
void gemm_mfma(const ushort* __restrict__ A, const ushort* __restrict__ Bt,
               float* __restrict__ C,
               const float* __restrict__ scores, const float* __restrict__ b2)
{
    __shared__ ushort Asm[128*32];
    __shared__ ushort Bsm[128*32];
    const int t = threadIdx.x, lane = t & 63, w = t >> 6;
    const int wr = w >> 1, wc = w & 1;
    const int row0 = blockIdx.x * 128, col0 = blockIdx.y * 128;

    const int lr = lane >> 2;
    const int lc = (lane & 3) ^ (lr & 3);
    const ushort* Ag0 = A  + (size_t)(row0 +      w*16 + lr) * 1024 + lc*8;
    const ushort* Ag1 = A  + (size_t)(row0 + 64 + w*16 + lr) * 1024 + lc*8;
    const ushort* Bg0 = Bt + (size_t)(col0 +      w*16 + lr) * 1024 + lc*8;
    const ushort* Bg1 = Bt + (size_t)(col0 + 64 + w*16 + lr) * 1024 + lc*8;
    ushort* Al0 = Asm + (     w*16) * 32;
    ushort* Al1 = Asm + (64 + w*16) * 32;
    ushort* Bl0 = Bsm + (     w*16) * 32;
    ushort* Bl1 = Bsm + (64 + w*16) * 32;

    f32x4 acc[4][4];
    #pragma unroll
    for (int i = 0; i < 4; ++i)
        #pragma unroll
        for (int j = 0; j < 4; ++j) acc[i][j] = (f32x4){0.f,0.f,0.f,0.f};

    const int quad = lane >> 4;
    const int fr   = lane & 15;
    const int fchk = (quad ^ (lane & 3)) * 8;

    for (int k0 = 0; k0 < 1024; k0 += 32) {
        __syncthreads();
        gl_lds16(Ag0 + k0, Al0);
        gl_lds16(Ag1 + k0, Al1);
        gl_lds16(Bg0 + k0, Bl0);
        gl_lds16(Bg1 + k0, Bl1);
        __syncthreads();

        bf16x8 af[4], bf[4];
        #pragma unroll
        for (int i = 0; i < 4; ++i) {
            af[i] = *(const bf16x8*)(Asm + (wr*64 + i*16 + fr)*32 + fchk);
            bf[i] = *(const bf16x8*)(Bsm + (wc*64 + i*16 + fr)*32 + fchk);
        }
        #pragma unroll
        for (int i = 0; i < 4; ++i)
            #pragma unroll
            for (int j = 0; j < 4; ++j)
                acc[i][j] = __builtin_amdgcn_mfma_f32_16x16x32_bf16(
                    af[i], bf[j], acc[i][j], 0, 0, 0);
    }

    float b2v[4][HH];
    #pragma unroll
    for (int tj = 0; tj < 4; ++tj) {
        const int col = col0 + wc*64 + tj*16 + fr;
        #pragma unroll
        for (int h = 0; h < HH; ++h) b2v[tj][h] = b2[(size_t)h*EE + col];
    }
    #pragma unroll
    for (int ti = 0; ti < 4; ++ti)
        #pragma unroll
        for (int i = 0; i < 4; ++i) {
            const int row = row0 + wr*64 + ti*16 + quad*4 + i;
            float sc[HH];
            #pragma unroll
            for (int h = 0; h < HH; ++h) sc[h] = scores[row*HH + h];
            #pragma unroll
            for (int tj = 0; tj < 4; ++tj) {
                const int col = col0 + wc*64 + tj*16 + fr;
                float bb = 0.f;
                #pragma unroll
                for (int h = 0; h < HH; ++h) bb = fmaf(sc[h], b2v[tj][h], bb);
                C[(size_t)row*1024 + col] = acc[ti][tj][i] + bb;
            }
        }
}

// ---------- batched per-head MFMA: h1 = gelu(hln@W1[h]+b1), + fused logits --
// Block covers 128 rows x the FULL head (N=128 = D), so the logit dot
// logit[row,h] = sum_col h1[row,col]*q[h,col] + c[h] is completed in-block:
// per-lane partials -> 4-level DPP row reduce -> LDS cross-wave combine.
// h1 written as bf16 (halves write + downstream read traffic).
__global__ __launch_bounds__(256)
void gemm_h1(const ushort* __restrict__ A, const ushort* __restrict__ Bt,
             const float* __restrict__ b1,
             const float* __restrict__ qv, const float* __restrict__ cv,
             ushort* __restrict__ h1b, float* __restrict__ logits)
{
    const int hh = blockIdx.z;
    __shared__ ushort Asm[128*32];
    __shared__ ushort Bsm[128*32];
    __shared__ float lpart[128][2];
    const int t = threadIdx.x, lane = t & 63, w = t >> 6;
    const int wr = w >> 1, wc = w & 1;
    const int row0 = blockIdx.x * 128;

    const int lr = lane >> 2;
    const int lc = (lane & 3) ^ (lr & 3);
    const ushort* Ag0 = A + (size_t)(row0 +      w*16 + lr) * 1024 + hh*DD + lc*8;
    const ushort* Ag1 = A + (size_t)(row0 + 64 + w*16 + lr) * 1024 + hh*DD + lc*8;
    const ushort* Bg0 = Bt + (size_t)hh*DD*DD + (     w*16 + lr) * DD + lc*8;
    const ushort* Bg1 = Bt + (size_t)hh*DD*DD + (64 + w*16 + lr) * DD + lc*8;
    ushort* Al0 = Asm + (     w*16) * 32;
    ushort* Al1 = Asm + (64 + w*16) * 32;
    ushort* Bl0 = Bsm + (     w*16) * 32;
    ushort* Bl1 = Bsm + (64 + w*16) * 32;

    f32x4 acc[4][4];
    #pragma unroll
    for (int i = 0; i < 4; ++i)
        #pragma unroll
        for (int j = 0; j < 4; ++j) acc[i][j] = (f32x4){0.f,0.f,0.f,0.f};

    const int quad = lane >> 4;
    const int fr   = lane & 15;
    const int fchk = (quad ^ (lane & 3)) * 8;

    for (int k0 = 0; k0 < 128; k0 += 32) {
        __syncthreads();
        gl_lds16(Ag0 + k0, Al0);
        gl_lds16(Ag1 + k0, Al1);
        gl_lds16(Bg0 + k0, Bl0);
        gl_lds16(Bg1 + k0, Bl1);
        __syncthreads();

        bf16x8 af[4], bf[4];
        #pragma unroll
        for (int i = 0; i < 4; ++i) {
            af[i] = *(const bf16x8*)(Asm + (wr*64 + i*16 + fr)*32 + fchk);
            bf[i] = *(const bf16x8*)(Bsm + (wc*64 + i*16 + fr)*32 + fchk);
        }
        #pragma unroll
        for (int i = 0; i < 4; ++i)
            #pragma unroll
            for (int j = 0; j < 4; ++j)
                acc[i][j] = __builtin_amdgcn_mfma_f32_16x16x32_bf16(
                    af[i], bf[j], acc[i][j], 0, 0, 0);
    }

    float colv[4], qh[4];
    #pragma unroll
    for (int tj = 0; tj < 4; ++tj) {
        const int col = wc*64 + tj*16 + fr;
        colv[tj] = b1[hh*DD + col];
        qh[tj]   = qv[hh*DD + col];
    }
    #pragma unroll
    for (int ti = 0; ti < 4; ++ti)
        #pragma unroll
        for (int i = 0; i < 4; ++i) {
            const int row = row0 + wr*64 + ti*16 + quad*4 + i;
            float p = 0.f;
            #pragma unroll
            for (int tj = 0; tj < 4; ++tj) {
                const int col = wc*64 + tj*16 + fr;
                float v = acc[ti][tj][i] + colv[tj];
                v = 0.5f * v * (1.f + erff(v * 0.70710678118654752f));
                h1b[(size_t)row*1024 + hh*DD + col] = f2bf(v);
                p = fmaf(v, qh[tj], p);
            }
            p = dpp_add(p, 0x111);
            p = dpp_add(p, 0x112);
            p = dpp_add(p, 0x114);
            p = dpp_add(p, 0x118);          // lane fr==15 of each quad: row sum
            if (fr == 15)
                lpart[wr*64 + ti*16 + quad*4 + i][wc] = p;
        }
    __syncthreads();
    if (t < 128)
        logits[(size_t)(row0 + t)*HH + hh] = lpart[t][0] + lpart[t][1] + cv[hh];
}

// ---------------------------------------------------------------- scan -----
// One wave per (b,h); lane owns d=2l,2l+1. States emitted as packed bf16 via
// v_perm (round-half-up). Chain-shortened recurrence (see r6). With a single
// in-order wave, total instruction count ~= time, so the epilogue pack is
// minimal: 2 adds + 1 v_perm + 1 store.
__global__ __launch_bounds__(64)
void scan_k(const float* __restrict__ z,
            const float* __restrict__ uh_d, const float* __restrict__ uz_d,
            const float* __restrict__ b_u,
            const float* __restrict__ lns_g, const float* __restrict__ lns_b,
            ushort* __restrict__ states)
{
    const int bh = blockIdx.x;
    const int b = bh >> 3, h = bh & 7;
    const int l = threadIdx.x;
    const int d0 = 2*l, d1 = d0 + 1;

    const float uhn0 = -uh_d[h*DD+d0] * LOG2E, uhn1 = -uh_d[h*DD+d1] * LOG2E;
    const float uzn0 = -uz_d[h*DD+d0] * LOG2E, uzn1 = -uz_d[h*DD+d1] * LOG2E;
    const float bun0 = -b_u [h*DD+d0] * LOG2E, bun1 = -b_u [h*DD+d1] * LOG2E;
    const float g0  = lns_g[d0], g1 = lns_g[d1];
    const float be0 = lns_b[d0], be1 = lns_b[d1];
    const float A0 = g0 * uhn0, A1 = g1 * uhn1;
    const float bunB0 = fmaf(be0, uhn0, bun0);    // bun + be*uhn
    const float bunB1 = fmaf(be1, uhn1, bun1);

    const float* zp = z + ((size_t)b * SS * HH + h) * DD + d0;
    unsigned* op = (unsigned*)(states + (size_t)b * SS * HD + h * DD) + l;

    const int CH = 8;
    float2 zc[CH], zn[CH];
    float pb0[CH], pb1[CH];
    #pragma unroll
    for (int i = 0; i < CH; ++i) zc[i] = *(const float2*)(zp + (size_t)i*HD);
    #pragma unroll
    for (int i = 0; i < CH; ++i) {
        pb0[i] = fmaf(zc[i].x, uzn0, bunB0);
        pb1[i] = fmaf(zc[i].y, uzn1, bunB1);
    }

    float r_c, wp0, wp1, W0, W1, dv0, dv1;

#define PACK_STORE(HP0, HP1, OFF) do {                                       \
        const unsigned pu0 = __float_as_uint(HP0) + 0x8000u;                 \
        const unsigned pu1 = __float_as_uint(HP1) + 0x8000u;                 \
        op[(size_t)(OFF) * (HD/2)] =                                         \
            __builtin_amdgcn_perm(pu1, pu0, 0x07060302u);                    \
    } while (0)

#define SCAN_STEP(ZX, ZY, PB0v, PB1v, ZNX, ZNY, OFF) do {                    \
        const float t0 = fmaf(r_c, W0, (PB0v));                              \
        const float t1 = fmaf(r_c, W1, (PB1v));                              \
        const float e0 = __builtin_amdgcn_exp2f(t0);                         \
        const float e1 = __builtin_amdgcn_exp2f(t1);                         \
        const float u0 = __builtin_amdgcn_rcpf(1.f + e0);                    \
        const float u1 = __builtin_amdgcn_rcpf(1.f + e1);                    \
        const float hn0 = fmaf(u0, dv0, (ZX));                               \
        const float hn1 = fmaf(u1, dv1, (ZY));                               \
        const float s1 = wave_sum64(hn0 + hn1);                              \
        const float s2 = wave_sum64(fmaf(hn0, hn0, hn1*hn1));                \
        const float m   = s1 * (1.f/128.f);                                  \
        const float var = fmaf(s2, 1.f/128.f, -m*m);                         \
        r_c = __builtin_amdgcn_rsqf(var + LNEPS);                            \
        wp0 = hn0 - m; wp1 = hn1 - m;                                        \
        W0 = wp0 * A0; W1 = wp1 * A1;                                        \
        const float hp0 = fmaf(wp0, r_c * g0, be0);                          \
        const float hp1 = fmaf(wp1, r_c * g1, be1);                          \
        PACK_STORE(hp0, hp1, OFF);                                           \
        dv0 = hp0 - (ZNX); dv1 = hp1 - (ZNY);                                \
    } while (0)

    // ---- peel step 0 (h_prev = 0) ----
    {
        const float z0 = zc[0].x, z1 = zc[0].y;
        const float t0 = fmaf(z0, uzn0, bun0);     // raw pre, no be*uhn term
        const float t1 = fmaf(z1, uzn1, bun1);
        const float e0 = __builtin_amdgcn_exp2f(t0);
        const float e1 = __builtin_amdgcn_exp2f(t1);
        const float u0 = __builtin_amdgcn_rcpf(1.f + e0);
        const float u1 = __builtin_amdgcn_rcpf(1.f + e1);
        const float hn0 = fmaf(u0, -z0, z0);       // u*(0-z)+z
        const float hn1 = fmaf(u1, -z1, z1);
        const float s1 = wave_sum64(hn0 + hn1);
        const float s2 = wave_sum64(fmaf(hn0, hn0, hn1*hn1));
        const float m   = s1 * (1.f/128.f);
        const float var = fmaf(s2, 1.f/128.f, -m*m);
        r_c = __builtin_amdgcn_rsqf(var + LNEPS);
        wp0 = hn0 - m; wp1 = hn1 - m;
        W0 = wp0 * A0; W1 = wp1 * A1;
        const float hp0 = fmaf(wp0, r_c * g0, be0);
        const float hp1 = fmaf(wp1, r_c * g1, be1);
        PACK_STORE(hp0, hp1, 0);
        dv0 = hp0 - zc[1].x; dv1 = hp1 - zc[1].y;
    }

    // ---- rest of chunk 0 (steps 1..7) ----
    #pragma unroll
    for (int i = 0; i < CH; ++i)
        zn[i] = *(const float2*)(zp + (size_t)(CH+i)*HD);
    #pragma unroll
    for (int i = 1; i < CH; ++i) {
        const float znx = (i+1 < CH) ? zc[i+1].x : zn[0].x;
        const float zny = (i+1 < CH) ? zc[i+1].y : zn[0].y;
        SCAN_STEP(zc[i].x, zc[i].y, pb0[i], pb1[i], znx, zny, i);
    }
    #pragma unroll
    for (int i = 0; i < CH; ++i) {
        zc[i] = zn[i];
        pb0[i] = fmaf(zn[i].x, uzn0, bunB0);
        pb1[i] = fmaf(zn[i].y, uzn1, bunB1);
    }

    // ---- chunks 1..255 ----
    for (int s0 = CH; s0 < SS; s0 += CH) {
        if (s0 + CH < SS) {
            #pragma unroll
            for (int i = 0; i < CH; ++i)
                zn[i] = *(const float2*)(zp + (size_t)(s0+CH+i)*HD);
        } else {
            #pragma unroll
            for (int i = 0; i < CH; ++i) zn[i] = make_float2(0.f, 0.f);
        }
        #pragma unroll
        for (int i = 0; i < CH; ++i) {
            const float znx = (i+1 < CH) ? zc[i+1].x : zn[0].x;
            const float zny = (i+1 < CH) ? zc[i+1].y : zn[0].y;
            SCAN_STEP(zc[i].x, zc[i].y, pb0[i], pb1[i], znx, zny, s0 + i);
        }
        #pragma unroll
        for (int i = 0; i < CH; ++i) {
            zc[i] = zn[i];
            pb0[i] = fmaf(zn[i].x, uzn0, bunB0);
            pb1[i] = fmaf(zn[i].y, uzn1, bunB1);
        }
    }
#undef SCAN_STEP
#undef PACK_STORE
}

// ------------------- per-head diag+LN: bf16 states -> bf16 hln -------------
__global__ __launch_bounds__(256)
void headln_k(const unsigned* __restrict__ st, const float* __restrict__ os_d,
              const float* __restrict__ ffg, const float* __restrict__ ffb,
              unsigned* __restrict__ hln)
{
    const int gid  = blockIdx.x * 256 + threadIdx.x;
    const int row  = gid >> 6;            // bs*H + h  (< 65536)
    const int l    = gid & 63;
    const int h = row & 7;
    const int d0 = 2*l, d1 = d0 + 1;
    const unsigned v = st[(size_t)row * 64 + l];
    const float x0 = bf2f((ushort)(v & 0xffff)) * os_d[h*DD + d0];
    const float x1 = bf2f((ushort)(v >> 16))    * os_d[h*DD + d1];
    float s1 = x0 + x1;
    float s2 = fmaf(x0, x0, x1*x1);
    #pragma unroll
    for (int off = 32; off > 0; off >>= 1) {
        s1 += __shfl_xor(s1, off, 64);
        s2 += __shfl_xor(s2, off, 64);
    }
    const float m   = s1 * (1.f/128.f);
    const float var = fmaf(s2, 1.f/128.f, -m*m);
    const float r   = rsqrtf(var + LNEPS);
    const float o0 = fmaf((x0 - m)*r, ffg[h*DD + d0], ffb[h*DD + d0]);
    const float o1 = fmaf((x1 - m)*r, ffg[h*DD + d1], ffb[h*DD + d1]);
    hln[(size_t)row * 64 + l] = (unsigned)f2bf(o0) | ((unsigned)f2bf(o1) << 16);
}

// ---------------------- softmax + scale bf16 h1 -> g (bf16) ----------------
__global__ __launch_bounds__(256)
void softscale_k(const ushort* __restrict__ h1b, const float* __restrict__ logits,
                 ushort* __restrict__ gb, float* __restrict__ scores)
{
    const int gid = blockIdx.x * 256 + threadIdx.x;
    const size_t idx = (size_t)gid * 4;
    const int bs = (int)(idx >> 10);
    const int h  = (int)((idx >> 7) & 7);
    float l[8];
    float mx = -1e30f;
    #pragma unroll
    for (int i = 0; i < 8; ++i) { l[i] = logits[bs*8 + i]; mx = fmaxf(mx, l[i]); }
    float den = 0.f;
    #pragma unroll
    for (int i = 0; i < 8; ++i) den += __expf(l[i] - mx);
    const float sc = __expf(l[h] - mx) / den;
    const ushort4 v = *(const ushort4*)(h1b + idx);
    ushort4 o;
    o.x = f2bf(bf2f(v.x) * sc); o.y = f2bf(bf2f(v.y) * sc);
    o.z = f2bf(bf2f(v.z) * sc); o.w = f2bf(bf2f(v.w) * sc);
    *(ushort4*)(gb + idx) = o;
    if ((idx & 127) == 0) scores[bs*8 + h] = sc;
}

// ---------------------------------------------------------------- final LN -
__global__ __launch_bounds__(256)
void finalln_k(const float* __restrict__ w, const float* __restrict__ g,
               const float* __restrict__ b, float* __restrict__ out)
{
    const int row = blockIdx.x;
    const int t = threadIdx.x;
    const float* xp = w + (size_t)row * EE;
    const float4 v = *(const float4*)(xp + t*4);
    float s1 = v.x + v.y + v.z + v.w;
    float s2 = v.x*v.x + v.y*v.y + v.z*v.z + v.w*v.w;
    #pragma unroll
    for (int off = 32; off > 0; off >>= 1) {
        s1 += __shfl_xor(s1, off, 64);
        s2 += __shfl_xor(s2, off, 64);
    }
    __shared__ float r1[4], r2[4];
    if ((t & 63) == 0) { r1[t>>6] = s1; r2[t>>6] = s2; }
    __syncthreads();
    s1 = r1[0] + r1[1] + r1[2] + r1[3];
    s2 = r2[0] + r2[1] + r2[2] + r2[3];
    const float m   = s1 * (1.f/1024.f);
    const float var = fmaf(s2, 1.f/1024.f, -m*m);
    const float r   = rsqrtf(var + LNEPS);
    const float4 gv = *(const float4*)(g + t*4);
    const float4 bv = *(const float4*)(b + t*4);
    float4 o;
    o.x = fmaf((v.x - m)*r, gv.x, bv.x);
    o.y = fmaf((v.y - m)*r, gv.y, bv.y);
    o.z = fmaf((v.z - m)*r, gv.z, bv.z);
    o.w = fmaf((v.w - m)*r, gv.w, bv.w);
    *(float4*)(out + (size_t)row*EE + t*4) = o;
}

// ---------------------------------------------------------------------------
extern "C" void kernel_launch(void* const* d_in, const int* in_sizes, int n_in,
                              void* d_out, int out_size, void* d_ws, size_t ws_size,
                              hipStream_t stream)
{
    const float* x       = (const float*)d_in[0];
    const float* W_ez    = (const float*)d_in[1];
    const float* b_ez    = (const float*)d_in[2];
    const float* U_h     = (const float*)d_in[3];
    const float* U_z     = (const float*)d_in[4];
    const float* b_u     = (const float*)d_in[5];
    const float* outsh   = (const float*)d_in[6];
    const float* lns_g   = (const float*)d_in[7];
    const float* lns_b   = (const float*)d_in[8];
    const float* ff_ln_g = (const float*)d_in[9];
    const float* ff_ln_b = (const float*)d_in[10];
    const float* ff_W1   = (const float*)d_in[11];
    const float* ff_b1   = (const float*)d_in[12];
    const float* ff_W2   = (const float*)d_in[13];
    const float* ff_b2   = (const float*)d_in[14];
    const float* w_att   = (const float*)d_in[15];
    const float* b_att   = (const float*)d_in[16];
    const float* lno_g   = (const float*)d_in[17];
    const float* lno_b   = (const float*)d_in[18];
    float* out = (float*)d_out;

    float* ws = (float*)d_ws;
    const size_t NBIG = (size_t)BSR * HD;          // 8M floats = 32 MB
    float* bufA = ws;                              // z (fp32) -> gb (bf16)
    float* bufB = ws + NBIG;                       // xb_hi/lo -> states+hln (bf16) -> weighted
    float* bufC = ws + 2*NBIG;                     // WezT hi/lo -> h1 (bf16)
    float* ext  = ws + 3*NBIG;
    ushort* W2t   = (ushort*)ext;                  // 1M ushorts (512K floats)
    ushort* W1t   = (ushort*)(ext + 512*1024);     // 128K ushorts (64K floats)
    float* logits = ext + 512*1024 + 64*1024;      // 64K
    float* scores = logits + BSR*HH;               // 64K
    float* qv     = scores + BSR*HH;               // 1024
    float* cv     = qv + HD;                       // 8
    float* uh_d   = cv + 8;
    float* uz_d   = uh_d + HD;
    float* os_d   = uz_d + HD;
    // lifetime-disjoint aliases:
    ushort* xb_hi = (ushort*)bufB;                 // dies after gemm_mfma_hp
    ushort* xb_lo = (ushort*)bufB + NBIG;
    ushort* stb   = (ushort*)bufB;                 // scan out (16 MB, packed bf16)
    ushort* hlnb  = (ushort*)bufB + NBIG;          // headln out (16 MB)
    float*  wsum  = bufB;                          // weighted (32 MB), after st/hln die
    ushort* WezT_hi = (ushort*)bufC;               // die after gemm_mfma_hp
    ushort* WezT_lo = (ushort*)bufC + 1024*1024;
    ushort* h1b   = (ushort*)bufC;                 // h1 bf16 after WezT dies
    ushort* gb    = (ushort*)bufA;                 // after z dies

    // 0: independent prep
    convx2_k<<<(BSR*EE/4)/256, 256, 0, stream>>>(x, xb_hi, xb_lo);
    prepall_k<<<2434, 256, 0, stream>>>(W_ez, WezT_hi, WezT_lo,
                                        ff_W2, W2t, ff_W1, W1t,
                                        w_att, ff_b2, b_att,
                                        U_h, U_z, outsh,
                                        qv, cv, uh_d, uz_d, os_d);
    // 1: z = tanh(x @ W_ez + b_ez)   [split-bf16 MFMA, fp32-class]
    gemm_mfma_hp<<<dim3(64, 8), 256, 0, stream>>>(
        xb_hi, xb_lo, WezT_hi, WezT_lo, bufA, b_ez);
    // 2: scan -> states (packed bf16)
    scan_k<<<BB*HH, 64, 0, stream>>>(bufA, uh_d, uz_d, b_u, lns_g, lns_b, stb);
    // 3: diag-scale + per-head LN -> hln bf16
    headln_k<<<(BSR*HH*64)/256, 256, 0, stream>>>(
        (const unsigned*)stb, os_d, ff_ln_g, ff_ln_b, (unsigned*)hlnb);
    // 4: h1 = gelu(hln @ W1[h] + b1[h]) [bf16 MFMA] + fused logits
    gemm_h1<<<dim3(64, 1, 8), 256, 0, stream>>>(hlnb, W1t, ff_b1, qv, cv,
                                                h1b, logits);
    // 5: softmax over heads, gb = bf16(score * h1), stash scores
    softscale_k<<<(BSR*HD/4)/256, 256, 0, stream>>>(h1b, logits, gb, scores);
    // 6: weighted = g @ W2 + sum_h score_h*b2[h,:]   [bf16 MFMA]
    gemm_mfma<<<dim3(64, 8), 256, 0, stream>>>(gb, W2t, wsum, scores, ff_b2);
    // 7: final LayerNorm over E -> out
    finalln_k<<<BSR, 256, 0, stream>>>(wsum, lno_g, lno_b, out);
}